// Round 2
// baseline (303.062 us; speedup 1.0000x reference)
//
#include <hip/hip_runtime.h>

typedef __attribute__((ext_vector_type(8))) short bf16x8;
typedef __attribute__((ext_vector_type(4))) float f32x4;

#define DEV static __device__ __forceinline__

DEV unsigned short f2bf(float f){
  union { float f; unsigned u; } v; v.f = f;
  unsigned r = v.u + 0x7fffu + ((v.u >> 16) & 1u);
  return (unsigned short)(r >> 16);
}
DEV float bf2f(unsigned short u){
  union { unsigned u; float f; } v; v.u = ((unsigned)u) << 16;
  return v.f;
}
DEV unsigned long long pk4(float a, float b, float c, float d){
  unsigned lo = (unsigned)f2bf(a) | ((unsigned)f2bf(b) << 16);
  unsigned hi = (unsigned)f2bf(c) | ((unsigned)f2bf(d) << 16);
  return ((unsigned long long)hi << 32) | lo;
}

// ---------------- transpose+convert: src [bat][R][C] f32 -> dst [bat][C][R] bf16
__global__ void k_tcvt(const float* __restrict__ src, unsigned short* __restrict__ dst,
                       int R, int C){
  __shared__ float tile[32][33];
  int bat = blockIdx.z;
  size_t boff = (size_t)bat * R * C;
  int c0 = blockIdx.x * 32, r0 = blockIdx.y * 32;
  int tx = threadIdx.x, ty = threadIdx.y;
  for (int i = 0; i < 4; i++)
    tile[ty + i*8][tx] = src[boff + (size_t)(r0 + ty + i*8) * C + c0 + tx];
  __syncthreads();
  for (int i = 0; i < 4; i++)
    dst[boff + (size_t)(c0 + ty + i*8) * R + r0 + tx] = f2bf(tile[tx][ty + i*8]);
}

// ---------------- x: straight bf16 copy (xb, [n][256]) + transposed bf16 (xT, [b][256][2048])
__global__ void k_xprep(const float* __restrict__ x, unsigned short* __restrict__ xb,
                        unsigned short* __restrict__ xT){
  __shared__ float tile[32][33];
  int bat = blockIdx.z;
  size_t boff = (size_t)bat * 2048 * 256;
  int c0 = blockIdx.x * 32, r0 = blockIdx.y * 32;
  int tx = threadIdx.x, ty = threadIdx.y;
  for (int i = 0; i < 4; i++){
    float v = x[boff + (size_t)(r0 + ty + i*8) * 256 + c0 + tx];
    tile[ty + i*8][tx] = v;
    xb[boff + (size_t)(r0 + ty + i*8) * 256 + c0 + tx] = f2bf(v);
  }
  __syncthreads();
  for (int i = 0; i < 4; i++)
    xT[boff + (size_t)(c0 + ty + i*8) * 2048 + r0 + tx] = f2bf(tile[tx][ty + i*8]);
}

// ---------------- router: logits -> softmax -> top2 -> normalized routing, transposed [bm][s]
__global__ __launch_bounds__(256) void k_router(const float* __restrict__ x,
                                                const float* __restrict__ Wr,
                                                const float* __restrict__ br,
                                                const float* __restrict__ bias0,
                                                float* __restrict__ routT){
  __shared__ float lg[32][8];
  __shared__ float rt[32][8];
  int t = threadIdx.x;
  int row = t >> 3, mm = t & 7;
  int n = blockIdx.x * 32 + row;                 // token 0..4095
  const float* xr = x + (size_t)n * 256;
  float acc = 0.f;
  for (int d = 0; d < 256; d++) acc += xr[d] * Wr[d * 8 + mm];
  acc += br[mm];
  lg[row][mm] = acc;
  __syncthreads();
  if (t < 32){
    int r = t; int n2 = blockIdx.x * 32 + r; int b = n2 >> 11;
    float mx = -1e30f;
    for (int i = 0; i < 8; i++) mx = fmaxf(mx, lg[r][i]);
    float s[8]; float sum = 0.f;
    for (int i = 0; i < 8; i++){ s[i] = __expf(lg[r][i] - mx); sum += s[i]; }
    for (int i = 0; i < 8; i++) s[i] /= sum;
    float bb[8];
    for (int i = 0; i < 8; i++) bb[i] = s[i] + bias0[b * 8 + i];
    int i1 = 0;
    for (int i = 1; i < 8; i++) if (bb[i] > bb[i1]) i1 = i;
    int i2 = -1;
    for (int i = 0; i < 8; i++){ if (i == i1) continue; if (i2 < 0 || bb[i] > bb[i2]) i2 = i; }
    float wsum = s[i1] + s[i2];
    for (int i = 0; i < 8; i++)
      rt[r][i] = (i == i1) ? s[i1] / wsum : ((i == i2) ? s[i2] / wsum : 0.f);
  }
  __syncthreads();
  {
    int n3 = blockIdx.x * 32 + row;
    int b = n3 >> 11, sl = n3 & 2047;
    routT[((size_t)b * 8 + mm) * 2048 + sl] = rt[row][mm];
  }
}

// ---------------- u[bm][d] = sum_s r * x ; rho[bm] = sum_s r
__global__ __launch_bounds__(256) void k_usum(const unsigned short* __restrict__ xT,
                                              const float* __restrict__ routT,
                                              float* __restrict__ u, float* __restrict__ rho){
  int bm = blockIdx.x, b = bm >> 3, t = threadIdx.x;
  const unsigned short* xr = xT + ((size_t)b * 256 + t) * 2048;
  const float* rr = routT + (size_t)bm * 2048;
  float acc = 0.f, rs = 0.f;
  for (int s8 = 0; s8 < 2048; s8 += 8){
    bf16x8 xv = *(const bf16x8*)(xr + s8);
    f32x4 r0 = *(const f32x4*)(rr + s8);
    f32x4 r1 = *(const f32x4*)(rr + s8 + 4);
    acc += bf2f((unsigned short)xv[0])*r0[0] + bf2f((unsigned short)xv[1])*r0[1]
         + bf2f((unsigned short)xv[2])*r0[2] + bf2f((unsigned short)xv[3])*r0[3]
         + bf2f((unsigned short)xv[4])*r1[0] + bf2f((unsigned short)xv[5])*r1[1]
         + bf2f((unsigned short)xv[6])*r1[2] + bf2f((unsigned short)xv[7])*r1[3];
    rs += r0[0]+r0[1]+r0[2]+r0[3]+r1[0]+r1[1]+r1[2]+r1[3];
  }
  u[(size_t)bm * 256 + t] = acc;
  if (t == 0) rho[bm] = rs;
}

// ---------------- ku[bm][hd] = WkT[m][hd]·u[bm], vu[bm][hd] = WvT[m][hd]·u[bm]
__global__ __launch_bounds__(256) void k_bias(const unsigned short* __restrict__ WkT,
                                              const unsigned short* __restrict__ WvT,
                                              const float* __restrict__ u,
                                              float* __restrict__ ku_g, float* __restrict__ vu_g){
  __shared__ float uL[256];
  int bid = blockIdx.x, t = threadIdx.x;
  int bm = bid >> 3, hseg = bid & 7, m = bm & 7;
  if (t < 64) *(f32x4*)(uL + t*4) = *(const f32x4*)(u + (size_t)bm*256 + t*4);
  __syncthreads();
  int hd = hseg * 256 + t;
  const unsigned short* wk = WkT + ((size_t)m*2048 + hd) * 256;
  const unsigned short* wv = WvT + ((size_t)m*2048 + hd) * 256;
  float sk = 0.f, sv = 0.f;
  for (int d8 = 0; d8 < 256; d8 += 8){
    bf16x8 a = *(const bf16x8*)(wk + d8);
    bf16x8 c = *(const bf16x8*)(wv + d8);
    for (int j = 0; j < 8; j++){
      sk += bf2f((unsigned short)a[j]) * uL[d8+j];
      sv += bf2f((unsigned short)c[j]) * uL[d8+j];
    }
  }
  ku_g[(size_t)bm*2048 + hd] = sk;
  vu_g[(size_t)bm*2048 + hd] = sv;
}

// ---------------- G partials: Gp[bm][kc][d2][d1] = sum_{s in chunk} (r x)[d1] x[d2]  (symmetric)
__global__ __launch_bounds__(1024) void k_gpart(const unsigned short* __restrict__ xT,
                                                const float* __restrict__ routT,
                                                unsigned short* __restrict__ Gp){
  __shared__ unsigned short stg[2][256*40];     // [0]=scaled A, [1]=unscaled B; 40 KB
  int bid = blockIdx.x;                          // 128 = b(2) m(8) kc(8)
  int kc = bid & 7, m = (bid >> 3) & 7, b = bid >> 6;
  int bm = b * 8 + m;
  int t = threadIdx.x, lane = t & 63, w = t >> 6;
  int li = lane & 15, lgp = lane >> 4;
  int r = w >> 2, c = w & 3;
  f32x4 acc[4][4];
  for (int i = 0; i < 4; i++) for (int j = 0; j < 4; j++) acc[i][j] = (f32x4){0,0,0,0};
  int srow = t >> 2, s8 = (t & 3) * 8;
  for (int sc = 0; sc < 8; sc++){
    int s0 = kc * 256 + sc * 32;
    bf16x8 xv = *(const bf16x8*)(xT + ((size_t)b*256 + srow)*2048 + s0 + s8);
    *(bf16x8*)(&stg[1][srow*40 + s8]) = xv;
    const float* rr = routT + (size_t)bm*2048 + s0 + s8;
    f32x4 ra = *(const f32x4*)rr, rb = *(const f32x4*)(rr + 4);
    bf16x8 sv;
    sv[0]=(short)f2bf(bf2f((unsigned short)xv[0])*ra[0]); sv[1]=(short)f2bf(bf2f((unsigned short)xv[1])*ra[1]);
    sv[2]=(short)f2bf(bf2f((unsigned short)xv[2])*ra[2]); sv[3]=(short)f2bf(bf2f((unsigned short)xv[3])*ra[3]);
    sv[4]=(short)f2bf(bf2f((unsigned short)xv[4])*rb[0]); sv[5]=(short)f2bf(bf2f((unsigned short)xv[5])*rb[1]);
    sv[6]=(short)f2bf(bf2f((unsigned short)xv[6])*rb[2]); sv[7]=(short)f2bf(bf2f((unsigned short)xv[7])*rb[3]);
    *(bf16x8*)(&stg[0][srow*40 + s8]) = sv;
    __syncthreads();
    bf16x8 Af[4], Bf[4];
    for (int i = 0; i < 4; i++) Af[i] = *(const bf16x8*)(&stg[0][(r*64+i*16+li)*40 + lgp*8]);
    for (int j = 0; j < 4; j++) Bf[j] = *(const bf16x8*)(&stg[1][(c*64+j*16+li)*40 + lgp*8]);
    for (int i = 0; i < 4; i++)
      for (int j = 0; j < 4; j++)
        acc[i][j] = __builtin_amdgcn_mfma_f32_16x16x32_bf16(Af[i], Bf[j], acc[i][j], 0, 0, 0);
    __syncthreads();
  }
  // 4-phase LDS bounce -> coalesced global writes
  unsigned short* Cs = &stg[0][0];               // [64][264]
  for (int ph = 0; ph < 4; ph++){
    if (c == ph){
      for (int i = 0; i < 4; i++)
        for (int j = 0; j < 4; j++){
          int rr2 = j*16 + li, cc2 = r*64 + i*16 + lgp*4;
          *(unsigned long long*)(&Cs[rr2*264 + cc2]) =
            pk4(acc[i][j][0], acc[i][j][1], acc[i][j][2], acc[i][j][3]);
        }
    }
    __syncthreads();
    for (int q = 0; q < 2; q++){
      int seg = t + q*1024; int row = seg >> 5, c16 = (seg & 31)*8;
      *(bf16x8*)(Gp + ((size_t)bm*8 + kc)*65536 + (size_t)(ph*64 + row)*256 + c16) =
        *(const bf16x8*)(&Cs[row*264 + c16]);
    }
    __syncthreads();
  }
}

// ---------------- reduce G partials over kc
__global__ __launch_bounds__(256) void k_gred(const unsigned short* __restrict__ Gp,
                                              unsigned short* __restrict__ G){
  int idx = blockIdx.x * 256 + threadIdx.x;      // 131072
  int bm = idx >> 13; size_t e8 = (size_t)(idx & 8191) * 8;
  float s[8] = {0,0,0,0,0,0,0,0};
  for (int kc = 0; kc < 8; kc++){
    bf16x8 v = *(const bf16x8*)(Gp + (((size_t)bm*8 + kc) << 16) + e8);
    for (int j = 0; j < 8; j++) s[j] += bf2f((unsigned short)v[j]);
  }
  unsigned long long lo = pk4(s[0], s[1], s[2], s[3]);
  unsigned long long hi = pk4(s[4], s[5], s[6], s[7]);
  *(unsigned long long*)(G + ((size_t)bm << 16) + e8) = lo;
  *(unsigned long long*)(G + ((size_t)bm << 16) + e8 + 4) = hi;
}

// ---------------- Q projection: Q[token][hd] = x @ Wq + bq (bf16 out)
__global__ __launch_bounds__(256) void k_qproj(const unsigned short* __restrict__ WqT,
                                               const unsigned short* __restrict__ xb,
                                               const float* __restrict__ bq,
                                               unsigned short* __restrict__ Q){
  int bid = blockIdx.x;                 // 2048 = 32 (hd blocks) * 64 (token blocks)
  int hdb = (bid & 31) * 64;
  int tkb = (bid >> 5) * 64;
  int t = threadIdx.x; int lane = t & 63, w = t >> 6;
  int li = lane & 15, lgp = lane >> 4;
  int tok0 = tkb + w * 16;
  f32x4 acc[4];
  for (int i = 0; i < 4; i++) acc[i] = (f32x4){0.f,0.f,0.f,0.f};
  const unsigned short* bptr = xb + (size_t)(tok0 + li) * 256 + lgp * 8;
  for (int kk = 0; kk < 8; kk++){
    bf16x8 bfr = *(const bf16x8*)(bptr + kk * 32);
    for (int ai = 0; ai < 4; ai++){
      bf16x8 afr = *(const bf16x8*)(WqT + (size_t)(hdb + ai*16 + li) * 256 + kk*32 + lgp*8);
      acc[ai] = __builtin_amdgcn_mfma_f32_16x16x32_bf16(afr, bfr, acc[ai], 0, 0, 0);
    }
  }
  int token = tok0 + li;
  for (int ai = 0; ai < 4; ai++){
    int hd0 = hdb + ai * 16 + lgp * 4;
    *(unsigned long long*)(Q + (size_t)token * 2048 + hd0) =
      pk4(acc[ai][0] + bq[hd0], acc[ai][1] + bq[hd0+1],
          acc[ai][2] + bq[hd0+2], acc[ai][3] + bq[hd0+3]);
  }
}

// ---------------- per-(b,m,h,vq): T = G @ Wv_h (vd slice); mem = Wk_h^T @ T + rank-1 bias terms
__global__ __launch_bounds__(1024) void k_memh(const unsigned short* __restrict__ G,
                                               const unsigned short* __restrict__ WkT,
                                               const unsigned short* __restrict__ WvT,
                                               const float* __restrict__ bk,
                                               const float* __restrict__ bv,
                                               const float* __restrict__ ku_g,
                                               const float* __restrict__ vu_g,
                                               const float* __restrict__ rho,
                                               unsigned short* __restrict__ mempart){
  __shared__ unsigned short Tt[64*256];          // 32 KB, XOR-swizzled [vd_loc][d]
  int bid = blockIdx.x;                           // 512 = b(2) m(8) h(8) vq(4)
  int vq = bid & 3, h = (bid >> 2) & 7, m = (bid >> 5) & 7, b = bid >> 8;
  int bm = b * 8 + m;
  int t = threadIdx.x, lane = t & 63, w = t >> 6;
  int li = lane & 15, lgp = lane >> 4;
  int r = w >> 2, c = w & 3;
  int vrow = c * 16 + li;                         // 0..63 (local vd)
  float rhov = rho[bm];
  // stage 1: T[d1][vd] = sum_d2 G[d1][d2] * WvT[vd][d2]
  f32x4 aT[4];
  for (int i = 0; i < 4; i++) aT[i] = (f32x4){0,0,0,0};
  for (int kk = 0; kk < 8; kk++){
    bf16x8 Bf = *(const bf16x8*)(WvT + ((size_t)m*2048 + h*256 + vq*64 + vrow)*256 + kk*32 + lgp*8);
    for (int i = 0; i < 4; i++){
      bf16x8 Af = *(const bf16x8*)(G + ((size_t)bm << 16) + (size_t)(r*64+i*16+li)*256 + kk*32 + lgp*8);
      aT[i] = __builtin_amdgcn_mfma_f32_16x16x32_bf16(Af, Bf, aT[i], 0, 0, 0);
    }
  }
  for (int i = 0; i < 4; i++){
    int d1 = r*64 + i*16 + lgp*4;
    int bo = (vrow*512 + d1*2) ^ ((vrow & 7) << 4);
    *(unsigned long long*)((char*)Tt + bo) = pk4(aT[i][0], aT[i][1], aT[i][2], aT[i][3]);
  }
  __syncthreads();
  // stage 2: mem[kd][vd] = sum_d WkT[kd][d] * Tt[vd][d]
  f32x4 a2[4];
  for (int i = 0; i < 4; i++) a2[i] = (f32x4){0,0,0,0};
  for (int kk = 0; kk < 8; kk++){
    int bo = (vrow*512 + (kk*32 + lgp*8)*2) ^ ((vrow & 7) << 4);
    bf16x8 Bf = *(const bf16x8*)((char*)Tt + bo);
    for (int i = 0; i < 4; i++){
      bf16x8 Af = *(const bf16x8*)(WkT + ((size_t)m*2048 + h*256 + r*64+i*16+li)*256 + kk*32 + lgp*8);
      a2[i] = __builtin_amdgcn_mfma_f32_16x16x32_bf16(Af, Bf, a2[i], 0, 0, 0);
    }
  }
  __syncthreads();
  // epilogue: + ku[kd]*bv[vd] + bk[kd]*(vu[vd] + rho*bv[vd]); overlay into Tt
  float bvv = bv[m*2048 + h*256 + vq*64 + vrow];
  float vuv = vu_g[(size_t)bm*2048 + h*256 + vq*64 + vrow];
  float bb = vuv + rhov * bvv;
  for (int i = 0; i < 4; i++){
    int kd = r*64 + i*16 + lgp*4;
    f32x4 ku4 = *(const f32x4*)(ku_g + (size_t)bm*2048 + h*256 + kd);
    f32x4 bk4 = *(const f32x4*)(bk + m*2048 + h*256 + kd);
    float v0 = a2[i][0] + ku4[0]*bvv + bk4[0]*bb;
    float v1 = a2[i][1] + ku4[1]*bvv + bk4[1]*bb;
    float v2 = a2[i][2] + ku4[2]*bvv + bk4[2]*bb;
    float v3 = a2[i][3] + ku4[3]*bvv + bk4[3]*bb;
    int bo = (vrow*512 + kd*2) ^ ((vrow & 7) << 4);
    *(unsigned long long*)((char*)Tt + bo) = pk4(v0, v1, v2, v3);
  }
  __syncthreads();
  // coalesced copy out: mempart[(b*8+h)*4+vq][m][64][256]
  size_t base = (((size_t)((b*8 + h)*4 + vq))*8 + m) * 16384;
  for (int q = 0; q < 2; q++){
    int seg = t + q*1024; int row = seg >> 5, c16 = (seg & 31)*8;
    int bo = (row*512 + c16*2) ^ ((row & 7) << 4);
    *(bf16x8*)(mempart + base + (size_t)row*256 + c16) = *(const bf16x8*)((char*)Tt + bo);
  }
}

// ---------------- reduce mem partials over m -> memT[b][h][vd][kd] bf16
__global__ __launch_bounds__(256) void k_mred(const unsigned short* __restrict__ mempart,
                                              unsigned short* __restrict__ memT){
  int idx = blockIdx.x * 256 + threadIdx.x;      // 131072
  int bh = idx >> 13; int rem = idx & 8191;
  int e8 = rem * 8;
  int vd = e8 >> 8, kd0 = e8 & 255;
  int vq = vd >> 6, vdl = vd & 63;
  size_t src = (((size_t)(bh*4 + vq))*8) * 16384 + (size_t)vdl*256 + kd0;
  float s[8] = {0,0,0,0,0,0,0,0};
  for (int m = 0; m < 8; m++){
    bf16x8 v = *(const bf16x8*)(mempart + src + (size_t)m*16384);
    for (int j = 0; j < 8; j++) s[j] += bf2f((unsigned short)v[j]);
  }
  unsigned long long lo = pk4(s[0], s[1], s[2], s[3]);
  unsigned long long hi = pk4(s[4], s[5], s[6], s[7]);
  *(unsigned long long*)(memT + (size_t)bh*65536 + e8) = lo;
  *(unsigned long long*)(memT + (size_t)bh*65536 + e8 + 4) = hi;
}

// ---------------- readout: O[token][h*256+vd] = sum_kd q[kd] * mem[kd][vd]
__global__ __launch_bounds__(256) void k_readout(const unsigned short* __restrict__ memT,
                                                 const unsigned short* __restrict__ Q,
                                                 unsigned short* __restrict__ O){
  int bid = blockIdx.x;                 // 512 = b(2) h(8) tokblk(32)
  int tb = bid & 31, h = (bid >> 5) & 7, b = bid >> 8;
  int t = threadIdx.x; int lane = t & 63, w = t >> 6;
  int li = lane & 15, lgp = lane >> 4;
  const unsigned short* mT = memT + (size_t)(b * 8 + h) * 65536;
  int vd0 = w * 64;
  int tokg = b * 2048 + tb * 64;
  f32x4 acc[4][4];
  for (int i = 0; i < 4; i++) for (int j = 0; j < 4; j++) acc[i][j] = (f32x4){0.f,0.f,0.f,0.f};
  for (int kk = 0; kk < 8; kk++){
    bf16x8 a[4], bb[4];
    for (int i = 0; i < 4; i++)
      a[i] = *(const bf16x8*)(mT + (size_t)(vd0 + i*16 + li) * 256 + kk*32 + lgp*8);
    for (int j = 0; j < 4; j++)
      bb[j] = *(const bf16x8*)(Q + (size_t)(tokg + j*16 + li) * 2048 + h*256 + kk*32 + lgp*8);
    for (int i = 0; i < 4; i++)
      for (int j = 0; j < 4; j++)
        acc[i][j] = __builtin_amdgcn_mfma_f32_16x16x32_bf16(a[i], bb[j], acc[i][j], 0, 0, 0);
  }
  for (int j = 0; j < 4; j++){
    int token = tokg + j * 16 + li;
    for (int i = 0; i < 4; i++){
      int vd = vd0 + i * 16 + lgp * 4;
      *(unsigned long long*)(O + (size_t)token * 2048 + h * 256 + vd) =
        pk4(acc[i][j][0], acc[i][j][1], acc[i][j][2], acc[i][j][3]);
    }
  }
}

// ---------------- final: out[token][dout] = O @ Wo + bo (f32 out)
__global__ __launch_bounds__(256) void k_final(const unsigned short* __restrict__ WoT,
                                               const unsigned short* __restrict__ O,
                                               const float* __restrict__ bo,
                                               float* __restrict__ out){
  int bid = blockIdx.x;                 // 256 = 4 (dout blocks) * 64 (token blocks)
  int db = (bid & 3) * 64, tkb = (bid >> 2) * 64;
  int t = threadIdx.x; int lane = t & 63, w = t >> 6;
  int li = lane & 15, lgp = lane >> 4;
  int tok0 = tkb + w * 16;
  f32x4 acc[4];
  for (int i = 0; i < 4; i++) acc[i] = (f32x4){0.f,0.f,0.f,0.f};
  for (int kk = 0; kk < 64; kk++){
    bf16x8 bfr = *(const bf16x8*)(O + (size_t)(tok0 + li) * 2048 + kk*32 + lgp*8);
    for (int ai = 0; ai < 4; ai++){
      bf16x8 afr = *(const bf16x8*)(WoT + (size_t)(db + ai*16 + li) * 2048 + kk*32 + lgp*8);
      acc[ai] = __builtin_amdgcn_mfma_f32_16x16x32_bf16(afr, bfr, acc[ai], 0, 0, 0);
    }
  }
  int token = tok0 + li;
  for (int ai = 0; ai < 4; ai++){
    int d0 = db + ai * 16 + lgp * 4;
    f32x4 v = acc[ai];
    v[0] += bo[d0]; v[1] += bo[d0+1]; v[2] += bo[d0+2]; v[3] += bo[d0+3];
    *(f32x4*)(out + (size_t)token * 256 + d0) = v;
  }
}

extern "C" void kernel_launch(void* const* d_in, const int* in_sizes, int n_in,
                              void* d_out, int out_size, void* d_ws, size_t ws_size,
                              hipStream_t stream) {
  const float* x     = (const float*)d_in[0];
  const float* Wq    = (const float*)d_in[1];
  const float* bq    = (const float*)d_in[2];
  const float* Wr    = (const float*)d_in[3];
  const float* br    = (const float*)d_in[4];
  const float* Wk    = (const float*)d_in[5];
  const float* bk    = (const float*)d_in[6];
  const float* Wv    = (const float*)d_in[7];
  const float* bv    = (const float*)d_in[8];
  const float* Wo    = (const float*)d_in[9];
  const float* bo    = (const float*)d_in[10];
  const float* bias0 = (const float*)d_in[11];
  float* out = (float*)d_out;

  char* ws = (char*)d_ws;
  size_t off = 0;
  auto alloc = [&](size_t bytes) -> char* {
    char* p = ws + off;
    off = (off + bytes + 255) & ~(size_t)255;
    return p;
  };
  unsigned short* xb   = (unsigned short*)alloc((size_t)4096 * 256 * 2);      // 2 MB
  unsigned short* xT   = (unsigned short*)alloc((size_t)2 * 256 * 2048 * 2);  // 2 MB
  unsigned short* WqT  = (unsigned short*)alloc((size_t)2048 * 256 * 2);      // 1 MB
  unsigned short* WkT  = (unsigned short*)alloc((size_t)8 * 2048 * 256 * 2);  // 8 MB
  unsigned short* WvT  = (unsigned short*)alloc((size_t)8 * 2048 * 256 * 2);  // 8 MB
  unsigned short* WoT  = (unsigned short*)alloc((size_t)256 * 2048 * 2);      // 1 MB
  unsigned short* Q    = (unsigned short*)alloc((size_t)4096 * 2048 * 2);     // 16 MB
  unsigned short* O    = (unsigned short*)alloc((size_t)4096 * 2048 * 2);     // 16 MB
  float*          routT= (float*)alloc((size_t)16 * 2048 * 4);                // 128 KB
  float*          u    = (float*)alloc((size_t)16 * 256 * 4);
  float*          rho  = (float*)alloc((size_t)16 * 4);
  float*          ku_g = (float*)alloc((size_t)16 * 2048 * 4);                // 128 KB
  float*          vu_g = (float*)alloc((size_t)16 * 2048 * 4);                // 128 KB
  unsigned short* Gp   = (unsigned short*)alloc((size_t)16 * 8 * 65536 * 2);  // 16.8 MB
  unsigned short* G    = (unsigned short*)alloc((size_t)16 * 65536 * 2);      // 2 MB
  unsigned short* memT = (unsigned short*)alloc((size_t)16 * 65536 * 2);      // 2 MB
  unsigned short* mempart = Gp;   // alias: Gp dead after k_gred, mempart written after
  (void)ws_size; (void)in_sizes; (void)n_in; (void)out_size;

  dim3 tb(32, 8, 1);
  // weights -> transposed bf16
  k_tcvt<<<dim3(64, 8, 1), tb, 0, stream>>>(Wq, WqT, 256, 2048);
  k_tcvt<<<dim3(64, 8, 8), tb, 0, stream>>>(Wk, WkT, 256, 2048);
  k_tcvt<<<dim3(64, 8, 8), tb, 0, stream>>>(Wv, WvT, 256, 2048);
  k_tcvt<<<dim3(8, 64, 1), tb, 0, stream>>>(Wo, WoT, 2048, 256);
  // x -> bf16 (straight + transposed)
  k_xprep<<<dim3(8, 64, 2), tb, 0, stream>>>(x, xb, xT);
  // router (transposed routing) + rank-1 bias helpers
  k_router<<<128, 256, 0, stream>>>(x, Wr, br, bias0, routT);
  k_usum<<<16, 256, 0, stream>>>(xT, routT, u, rho);
  k_bias<<<128, 256, 0, stream>>>(WkT, WvT, u, ku_g, vu_g);
  // G = X^T diag(r) X  (per b,m)
  k_gpart<<<128, 1024, 0, stream>>>(xT, routT, Gp);
  k_gred<<<512, 256, 0, stream>>>(Gp, G);
  // Q projection
  k_qproj<<<2048, 256, 0, stream>>>(WqT, xb, bq, Q);
  // mem = Wk^T G Wv + bias rank-1 terms (per b,m,h, vd-quarter), then reduce over m
  k_memh<<<512, 1024, 0, stream>>>(G, WkT, WvT, bk, bv, ku_g, vu_g, rho, mempart);
  k_mred<<<512, 256, 0, stream>>>(mempart, memT);
  // readout + output projection
  k_readout<<<512, 256, 0, stream>>>(memT, Q, O);
  k_final<<<256, 256, 0, stream>>>(WoT, O, bo, out);
}

// Round 3
// 282.107 us; speedup vs baseline: 1.0743x; 1.0743x over previous
//
#include <hip/hip_runtime.h>

typedef __attribute__((ext_vector_type(8))) short bf16x8;
typedef __attribute__((ext_vector_type(4))) float f32x4;

#define DEV static __device__ __forceinline__

DEV unsigned short f2bf(float f){
  union { float f; unsigned u; } v; v.f = f;
  unsigned r = v.u + 0x7fffu + ((v.u >> 16) & 1u);
  return (unsigned short)(r >> 16);
}
DEV float bf2f(unsigned short u){
  union { unsigned u; float f; } v; v.u = ((unsigned)u) << 16;
  return v.f;
}
DEV unsigned long long pk4(float a, float b, float c, float d){
  unsigned lo = (unsigned)f2bf(a) | ((unsigned)f2bf(b) << 16);
  unsigned hi = (unsigned)f2bf(c) | ((unsigned)f2bf(d) << 16);
  return ((unsigned long long)hi << 32) | lo;
}

// =============== fused prep: weight transposes/converts + x prep + router ===============
__global__ __launch_bounds__(256) void k_prep(const float* __restrict__ x,
                                              const float* __restrict__ Wq,
                                              const float* __restrict__ Wr,
                                              const float* __restrict__ br,
                                              const float* __restrict__ Wk,
                                              const float* __restrict__ Wv,
                                              const float* __restrict__ Wo,
                                              const float* __restrict__ bias0,
                                              unsigned short* __restrict__ WkT,
                                              unsigned short* __restrict__ WvT,
                                              unsigned short* __restrict__ WoT,
                                              unsigned short* __restrict__ Wqb,
                                              unsigned short* __restrict__ xb,
                                              unsigned short* __restrict__ xT,
                                              float* __restrict__ routT){
  __shared__ float tile[32*33];
  __shared__ float lg[32][8];
  __shared__ float rt2[32][8];
  int bid = blockIdx.x;
  int t = threadIdx.x;
  int tx = t & 31, ty = t >> 5;

  if (bid < 8192){                      // Wk (0..4095) / Wv (4096..8191): [8][256][2048] -> [8][2048][256]
    const float* src = (bid < 4096) ? Wk : Wv;
    unsigned short* dst = (bid < 4096) ? WkT : WvT;
    int q = bid & 4095;
    int bat = q >> 9, rem = q & 511;
    int c0 = (rem >> 3) * 32, r0 = (rem & 7) * 32;
    size_t boff = (size_t)bat * 256 * 2048;
    for (int i = 0; i < 4; i++)
      tile[(ty + i*8)*33 + tx] = src[boff + (size_t)(r0 + ty + i*8) * 2048 + c0 + tx];
    __syncthreads();
    for (int i = 0; i < 4; i++)
      dst[boff + (size_t)(c0 + ty + i*8) * 256 + r0 + tx] = f2bf(tile[tx*33 + ty + i*8]);
  } else if (bid < 8704){               // Wo: [2048][256] -> [256][2048]
    int q = bid - 8192;
    int c0 = (q >> 6) * 32, r0 = (q & 63) * 32;
    for (int i = 0; i < 4; i++)
      tile[(ty + i*8)*33 + tx] = Wo[(size_t)(r0 + ty + i*8) * 256 + c0 + tx];
    __syncthreads();
    for (int i = 0; i < 4; i++)
      WoT[(size_t)(c0 + ty + i*8) * 2048 + r0 + tx] = f2bf(tile[tx*33 + ty + i*8]);
  } else if (bid < 8960){               // Wq plain convert [256][2048]
    int q = bid - 8704;
    size_t idx = (size_t)q * 2048 + t * 8;
    f32x4 a = *(const f32x4*)(Wq + idx);
    f32x4 b = *(const f32x4*)(Wq + idx + 4);
    *(unsigned long long*)(Wqb + idx)     = pk4(a[0], a[1], a[2], a[3]);
    *(unsigned long long*)(Wqb + idx + 4) = pk4(b[0], b[1], b[2], b[3]);
  } else if (bid < 9984){               // x: [2][2048][256] -> xb [4096][256] + xT [2][256][2048]
    int q = bid - 8960;
    int bat = q >> 9, rem = q & 511;
    int c0 = (rem >> 6) * 32, r0 = (rem & 63) * 32;
    size_t boff = (size_t)bat * 2048 * 256;
    for (int i = 0; i < 4; i++){
      float v = x[boff + (size_t)(r0 + ty + i*8) * 256 + c0 + tx];
      tile[(ty + i*8)*33 + tx] = v;
      xb[boff + (size_t)(r0 + ty + i*8) * 256 + c0 + tx] = f2bf(v);
    }
    __syncthreads();
    for (int i = 0; i < 4; i++)
      xT[(size_t)(bat*256 + c0 + ty + i*8) * 2048 + r0 + tx] = f2bf(tile[tx*33 + ty + i*8]);
  } else {                              // router: 128 blocks, 32 tokens each
    int row = t >> 3, mm = t & 7;
    int n = (bid - 9984) * 32 + row;
    const float* xr = x + (size_t)n * 256;
    float acc = 0.f;
    for (int d = 0; d < 256; d++) acc += xr[d] * Wr[d * 8 + mm];
    acc += br[mm];
    lg[row][mm] = acc;
    __syncthreads();
    if (t < 32){
      int r = t; int n2 = (bid - 9984) * 32 + r; int b = n2 >> 11;
      float mx = -1e30f;
      for (int i = 0; i < 8; i++) mx = fmaxf(mx, lg[r][i]);
      float s[8]; float sum = 0.f;
      for (int i = 0; i < 8; i++){ s[i] = __expf(lg[r][i] - mx); sum += s[i]; }
      for (int i = 0; i < 8; i++) s[i] /= sum;
      float bb[8];
      for (int i = 0; i < 8; i++) bb[i] = s[i] + bias0[b * 8 + i];
      int i1 = 0;
      for (int i = 1; i < 8; i++) if (bb[i] > bb[i1]) i1 = i;
      int i2 = -1;
      for (int i = 0; i < 8; i++){ if (i == i1) continue; if (i2 < 0 || bb[i] > bb[i2]) i2 = i; }
      float wsum = s[i1] + s[i2];
      for (int i = 0; i < 8; i++)
        rt2[r][i] = (i == i1) ? s[i1] / wsum : ((i == i2) ? s[i2] / wsum : 0.f);
    }
    __syncthreads();
    int n3 = (bid - 9984) * 32 + row;
    int b = n3 >> 11, sl = n3 & 2047;
    routT[((size_t)b * 8 + mm) * 2048 + sl] = rt2[row][mm];
  }
}

// =============== u[bm][d] = sum_s r*x ; rho[bm] = sum_s r ===============
__global__ __launch_bounds__(256) void k_usum(const unsigned short* __restrict__ xT,
                                              const float* __restrict__ routT,
                                              float* __restrict__ u, float* __restrict__ rho){
  int bm = blockIdx.x, b = bm >> 3, t = threadIdx.x;
  const unsigned short* xr = xT + ((size_t)b * 256 + t) * 2048;
  const float* rr = routT + (size_t)bm * 2048;
  float acc = 0.f, rs = 0.f;
  for (int s8 = 0; s8 < 2048; s8 += 8){
    bf16x8 xv = *(const bf16x8*)(xr + s8);
    f32x4 r0 = *(const f32x4*)(rr + s8);
    f32x4 r1 = *(const f32x4*)(rr + s8 + 4);
    acc += bf2f((unsigned short)xv[0])*r0[0] + bf2f((unsigned short)xv[1])*r0[1]
         + bf2f((unsigned short)xv[2])*r0[2] + bf2f((unsigned short)xv[3])*r0[3]
         + bf2f((unsigned short)xv[4])*r1[0] + bf2f((unsigned short)xv[5])*r1[1]
         + bf2f((unsigned short)xv[6])*r1[2] + bf2f((unsigned short)xv[7])*r1[3];
    rs += r0[0]+r0[1]+r0[2]+r0[3]+r1[0]+r1[1]+r1[2]+r1[3];
  }
  u[(size_t)bm * 256 + t] = acc;
  if (t == 0) rho[bm] = rs;
}

// =============== ku/vu = WkT/WvT . u ===============
__global__ __launch_bounds__(256) void k_bias(const unsigned short* __restrict__ WkT,
                                              const unsigned short* __restrict__ WvT,
                                              const float* __restrict__ u,
                                              float* __restrict__ ku_g, float* __restrict__ vu_g){
  __shared__ float uL[256];
  int bid = blockIdx.x, t = threadIdx.x;
  int bm = bid >> 3, hseg = bid & 7, m = bm & 7;
  if (t < 64) *(f32x4*)(uL + t*4) = *(const f32x4*)(u + (size_t)bm*256 + t*4);
  __syncthreads();
  int hd = hseg * 256 + t;
  const unsigned short* wk = WkT + ((size_t)m*2048 + hd) * 256;
  const unsigned short* wv = WvT + ((size_t)m*2048 + hd) * 256;
  float sk = 0.f, sv = 0.f;
  for (int d8 = 0; d8 < 256; d8 += 8){
    bf16x8 a = *(const bf16x8*)(wk + d8);
    bf16x8 c = *(const bf16x8*)(wv + d8);
    for (int j = 0; j < 8; j++){
      sk += bf2f((unsigned short)a[j]) * uL[d8+j];
      sv += bf2f((unsigned short)c[j]) * uL[d8+j];
    }
  }
  ku_g[(size_t)bm*2048 + hd] = sk;
  vu_g[(size_t)bm*2048 + hd] = sv;
}

// =============== Gp[bm][kc] = X_chunk^T diag(r) X_chunk (256x256, K=256 tokens) ===============
__global__ __launch_bounds__(512) void k_gpart(const unsigned short* __restrict__ xT,
                                               const float* __restrict__ routT,
                                               unsigned short* __restrict__ Gp){
  __shared__ unsigned short As[256*72];     // scaled, 36 KB
  __shared__ unsigned short Bs[256*72];     // unscaled, 36 KB
  __shared__ float rl[64];
  int bid = blockIdx.x;                      // 128 = b(2) m(8) kc(8)
  int kc = bid & 7, m = (bid >> 3) & 7, b = bid >> 6;
  int bm = b * 8 + m;
  int t = threadIdx.x, lane = t & 63, w = t >> 6;
  int li = lane & 15, lgp = lane >> 4;
  int p = w >> 2, q = w & 3;
  f32x4 acc[8][4];
  for (int i = 0; i < 8; i++) for (int j = 0; j < 4; j++) acc[i][j] = (f32x4){0,0,0,0};
  for (int c4 = 0; c4 < 4; c4++){
    int s0 = kc * 256 + c4 * 64;
    if (t < 64) rl[t] = routT[(size_t)bm*2048 + s0 + t];
    __syncthreads();
    for (int qq = 0; qq < 4; qq++){
      int idx = t + qq*512;
      int row = idx >> 3, sc = (idx & 7) * 8;
      bf16x8 xv = *(const bf16x8*)(xT + ((size_t)(b*256 + row))*2048 + s0 + sc);
      *(bf16x8*)(&Bs[row*72 + sc]) = xv;
      f32x4 r0 = *(const f32x4*)(rl + sc);
      f32x4 r1 = *(const f32x4*)(rl + sc + 4);
      bf16x8 sv;
      sv[0]=(short)f2bf(bf2f((unsigned short)xv[0])*r0[0]);
      sv[1]=(short)f2bf(bf2f((unsigned short)xv[1])*r0[1]);
      sv[2]=(short)f2bf(bf2f((unsigned short)xv[2])*r0[2]);
      sv[3]=(short)f2bf(bf2f((unsigned short)xv[3])*r0[3]);
      sv[4]=(short)f2bf(bf2f((unsigned short)xv[4])*r1[0]);
      sv[5]=(short)f2bf(bf2f((unsigned short)xv[5])*r1[1]);
      sv[6]=(short)f2bf(bf2f((unsigned short)xv[6])*r1[2]);
      sv[7]=(short)f2bf(bf2f((unsigned short)xv[7])*r1[3]);
      *(bf16x8*)(&As[row*72 + sc]) = sv;
    }
    __syncthreads();
    for (int kk = 0; kk < 2; kk++){
      bf16x8 Bf[4];
      for (int j = 0; j < 4; j++)
        Bf[j] = *(const bf16x8*)(&Bs[(q*64 + j*16 + li)*72 + kk*32 + lgp*8]);
      for (int i = 0; i < 8; i++){
        bf16x8 Af = *(const bf16x8*)(&As[(p*128 + i*16 + li)*72 + kk*32 + lgp*8]);
        for (int j = 0; j < 4; j++)
          acc[i][j] = __builtin_amdgcn_mfma_f32_16x16x32_bf16(Af, Bf[j], acc[i][j], 0, 0, 0);
      }
    }
    __syncthreads();
  }
  // bounce C (row=d1 from A, col=d2 from B) -> Gp[bm][kc][d2][d1]
  unsigned short* Cs = As;                   // 64 x 264 overlay
  for (int ph = 0; ph < 4; ph++){
    if (q == ph){
      for (int i = 0; i < 8; i++)
        for (int j = 0; j < 4; j++){
          int rr = j*16 + li, cc = p*128 + i*16 + lgp*4;
          *(unsigned long long*)(&Cs[rr*264 + cc]) =
            pk4(acc[i][j][0], acc[i][j][1], acc[i][j][2], acc[i][j][3]);
        }
    }
    __syncthreads();
    for (int qq = 0; qq < 4; qq++){
      int idx = t + qq*512;
      int row = idx >> 5, cc = (idx & 31) * 8;
      *(bf16x8*)(Gp + (((size_t)bm*8 + kc) << 16) + (size_t)(ph*64 + row)*256 + cc) =
        *(const bf16x8*)(&Cs[row*264 + cc]);
    }
    __syncthreads();
  }
}

// =============== reduce Gp over kc -> G[bm][256][256] ===============
__global__ __launch_bounds__(256) void k_gred(const unsigned short* __restrict__ Gp,
                                              unsigned short* __restrict__ G){
  int idx = blockIdx.x * 256 + threadIdx.x;
  int bm = idx >> 13; size_t e8 = (size_t)(idx & 8191) * 8;
  float s[8] = {0,0,0,0,0,0,0,0};
  for (int kc = 0; kc < 8; kc++){
    bf16x8 v = *(const bf16x8*)(Gp + (((size_t)bm*8 + kc) << 16) + e8);
    for (int j = 0; j < 8; j++) s[j] += bf2f((unsigned short)v[j]);
  }
  *(unsigned long long*)(G + ((size_t)bm << 16) + e8)     = pk4(s[0], s[1], s[2], s[3]);
  *(unsigned long long*)(G + ((size_t)bm << 16) + e8 + 4) = pk4(s[4], s[5], s[6], s[7]);
}

// =============== per (b,m,h,vh): T = G@Wv (LDS), mem_part = Wk^T@T + rank-1 ===============
__global__ __launch_bounds__(512) void k_memh(const unsigned short* __restrict__ G,
                                              const unsigned short* __restrict__ WkT,
                                              const unsigned short* __restrict__ WvT,
                                              const float* __restrict__ bk,
                                              const float* __restrict__ bv,
                                              const float* __restrict__ ku_g,
                                              const float* __restrict__ vu_g,
                                              const float* __restrict__ rho,
                                              unsigned short* __restrict__ mempart){
  __shared__ unsigned short TT[128*256];     // 64 KB, XOR-swizzled [vd][d1]
  int bid = blockIdx.x;                       // 256 = b(2) m(8) h(8) vq(2)
  int vq = bid & 1, h = (bid >> 1) & 7, m = (bid >> 4) & 7, b = bid >> 7;
  int bm = b * 8 + m, bh = b * 8 + h;
  int hd0 = h * 256, vd0 = vq * 128;
  int t = threadIdx.x, lane = t & 63, w = t >> 6;
  int li = lane & 15, lgp = lane >> 4;
  int r = w >> 2, c = w & 3;
  // stage 1: T[d1 256][vd 128] = G @ Wv_slice
  f32x4 a1[8][2];
  for (int i = 0; i < 8; i++) for (int j = 0; j < 2; j++) a1[i][j] = (f32x4){0,0,0,0};
  for (int kk = 0; kk < 8; kk++){
    bf16x8 Bf[2];
    for (int j = 0; j < 2; j++)
      Bf[j] = *(const bf16x8*)(WvT + ((size_t)m*2048 + hd0 + vd0 + c*32 + j*16 + li)*256 + kk*32 + lgp*8);
    for (int i = 0; i < 8; i++){
      bf16x8 Af = *(const bf16x8*)(G + ((size_t)bm << 16) + (size_t)(r*128 + i*16 + li)*256 + kk*32 + lgp*8);
      for (int j = 0; j < 2; j++)
        a1[i][j] = __builtin_amdgcn_mfma_f32_16x16x32_bf16(Af, Bf[j], a1[i][j], 0, 0, 0);
    }
  }
  for (int i = 0; i < 8; i++)
    for (int j = 0; j < 2; j++){
      int vdl = c*32 + j*16 + li;
      int d1 = r*128 + i*16 + lgp*4;
      int bo2 = (vdl*512 + d1*2) ^ ((vdl & 7) << 4);
      *(unsigned long long*)((char*)TT + bo2) = pk4(a1[i][j][0], a1[i][j][1], a1[i][j][2], a1[i][j][3]);
    }
  __syncthreads();
  // stage 2: mem[kd 256][vd 128] = Wk^T @ T
  f32x4 a2[8][2];
  for (int i = 0; i < 8; i++) for (int j = 0; j < 2; j++) a2[i][j] = (f32x4){0,0,0,0};
  for (int kk = 0; kk < 8; kk++){
    bf16x8 Bf[2];
    for (int j = 0; j < 2; j++){
      int vdl = c*32 + j*16 + li;
      int bo2 = (vdl*512 + (kk*32 + lgp*8)*2) ^ ((vdl & 7) << 4);
      Bf[j] = *(const bf16x8*)((char*)TT + bo2);
    }
    for (int i = 0; i < 8; i++){
      bf16x8 Af = *(const bf16x8*)(WkT + ((size_t)m*2048 + hd0 + r*128 + i*16 + li)*256 + kk*32 + lgp*8);
      for (int j = 0; j < 2; j++)
        a2[i][j] = __builtin_amdgcn_mfma_f32_16x16x32_bf16(Af, Bf[j], a2[i][j], 0, 0, 0);
    }
  }
  __syncthreads();
  // epilogue (rank-1 bias terms) + coalescing bounce
  float rhov = rho[bm];
  unsigned short* Cs = TT;                    // 32 x 264 overlay
  for (int ph = 0; ph < 4; ph++){
    if (c == ph){
      for (int j = 0; j < 2; j++){
        int vdl = c*32 + j*16 + li;
        int vdg = hd0 + vd0 + vdl;
        float bvv = bv[(size_t)m*2048 + vdg];
        float vuv = vu_g[(size_t)bm*2048 + vdg];
        float bb = vuv + rhov * bvv;
        for (int i = 0; i < 8; i++){
          int kd = r*128 + i*16 + lgp*4;
          f32x4 ku4 = *(const f32x4*)(ku_g + (size_t)bm*2048 + hd0 + kd);
          f32x4 bk4 = *(const f32x4*)(bk + (size_t)m*2048 + hd0 + kd);
          float v0 = a2[i][j][0] + ku4[0]*bvv + bk4[0]*bb;
          float v1 = a2[i][j][1] + ku4[1]*bvv + bk4[1]*bb;
          float v2 = a2[i][j][2] + ku4[2]*bvv + bk4[2]*bb;
          float v3 = a2[i][j][3] + ku4[3]*bvv + bk4[3]*bb;
          *(unsigned long long*)(&Cs[(j*16 + li)*264 + kd]) = pk4(v0, v1, v2, v3);
        }
      }
    }
    __syncthreads();
    for (int qq = 0; qq < 2; qq++){
      int idx = t + qq*512;
      int row = idx >> 5, cc = (idx & 31) * 8;
      *(bf16x8*)(mempart + ((size_t)((bh*2 + vq)*8 + m))*32768 + (size_t)(ph*32 + row)*256 + cc) =
        *(const bf16x8*)(&Cs[row*264 + cc]);
    }
    __syncthreads();
  }
}

// =============== reduce mempart over m -> memT[bh][vd][kd] ===============
__global__ __launch_bounds__(256) void k_mred(const unsigned short* __restrict__ mempart,
                                              unsigned short* __restrict__ memT){
  int idx = blockIdx.x * 256 + threadIdx.x;   // 131072
  int bh = idx >> 13; int rem = idx & 8191;
  int vd = rem >> 5, kd0 = (rem & 31) * 8;
  int vq = vd >> 7, vdl = vd & 127;
  size_t src = ((size_t)((bh*2 + vq)*8))*32768 + (size_t)vdl*256 + kd0;
  float s[8] = {0,0,0,0,0,0,0,0};
  for (int m = 0; m < 8; m++){
    bf16x8 v = *(const bf16x8*)(mempart + src + (size_t)m*32768);
    for (int j = 0; j < 8; j++) s[j] += bf2f((unsigned short)v[j]);
  }
  size_t dst = (size_t)bh*65536 + (size_t)vd*256 + kd0;
  *(unsigned long long*)(memT + dst)     = pk4(s[0], s[1], s[2], s[3]);
  *(unsigned long long*)(memT + dst + 4) = pk4(s[4], s[5], s[6], s[7]);
}

// =============== E_h = Wq_h @ mem_h  -> Eb[b][d][h*256+vd]; qbAll = bq_h . mem_h ===============
__global__ __launch_bounds__(512) void k_emat(const unsigned short* __restrict__ memT,
                                              const unsigned short* __restrict__ Wqb,
                                              const float* __restrict__ bq,
                                              unsigned short* __restrict__ Eb,
                                              float* __restrict__ qbAll){
  __shared__ unsigned short Cs[32*264];
  int bid = blockIdx.x;                        // 32 = bh(16) * dseg(2)
  int dseg = bid & 1, bh = bid >> 1;
  int b = bh >> 3, h = bh & 7;
  int hd0 = h * 256, d0 = dseg * 128;
  int t = threadIdx.x, lane = t & 63, w = t >> 6;
  int li = lane & 15, lgp = lane >> 4;
  int r = w >> 2, c = w & 3;
  // out [vd 256][d 128]: A = memT rows vd, B = Wqb rows d (K = kd 256)
  f32x4 acc[8][2];
  for (int i = 0; i < 8; i++) for (int j = 0; j < 2; j++) acc[i][j] = (f32x4){0,0,0,0};
  for (int kk = 0; kk < 8; kk++){
    bf16x8 Bf[2];
    for (int j = 0; j < 2; j++)
      Bf[j] = *(const bf16x8*)(Wqb + (size_t)(d0 + c*32 + j*16 + li)*2048 + hd0 + kk*32 + lgp*8);
    for (int i = 0; i < 8; i++){
      bf16x8 Af = *(const bf16x8*)(memT + (size_t)bh*65536 + (size_t)(r*128 + i*16 + li)*256 + kk*32 + lgp*8);
      for (int j = 0; j < 2; j++)
        acc[i][j] = __builtin_amdgcn_mfma_f32_16x16x32_bf16(Af, Bf[j], acc[i][j], 0, 0, 0);
    }
  }
  // qb: qbAll[b][hd0+vd] = sum_kd bq[hd0+kd]*mem[kd][vd]
  if (dseg == 0 && t < 256){
    const unsigned short* mrow = memT + (size_t)bh*65536 + (size_t)t*256;
    float s = 0.f;
    for (int k8 = 0; k8 < 256; k8 += 8){
      bf16x8 v = *(const bf16x8*)(mrow + k8);
      for (int e = 0; e < 8; e++) s += bf2f((unsigned short)v[e]) * bq[hd0 + k8 + e];
    }
    qbAll[(size_t)b*2048 + hd0 + t] = s;
  }
  // bounce: C row=vd, col=d -> Eb[b][d][hd0+vd]
  for (int ph = 0; ph < 4; ph++){
    if (c == ph){
      for (int i = 0; i < 8; i++)
        for (int j = 0; j < 2; j++){
          int dl = j*16 + li;
          int vd4 = r*128 + i*16 + lgp*4;
          *(unsigned long long*)(&Cs[dl*264 + vd4]) =
            pk4(acc[i][j][0], acc[i][j][1], acc[i][j][2], acc[i][j][3]);
        }
    }
    __syncthreads();
    for (int qq = 0; qq < 2; qq++){
      int idx = t + qq*512;
      int row = idx >> 5, cc = (idx & 31) * 8;
      *(bf16x8*)(Eb + (size_t)b*524288 + (size_t)(d0 + ph*32 + row)*2048 + hd0 + cc) =
        *(const bf16x8*)(&Cs[row*264 + cc]);
    }
    __syncthreads();
  }
}

// =============== F += Eb @ WoT^T (split-K atomic, f32); c0 += qbAll.Wo + bo ===============
__global__ __launch_bounds__(512) void k_fmat(const unsigned short* __restrict__ Eb,
                                              const unsigned short* __restrict__ WoT,
                                              const float* __restrict__ qbAll,
                                              const float* __restrict__ bo,
                                              float* __restrict__ Facc,
                                              float* __restrict__ c0acc){
  int bid = blockIdx.x;                        // 16 = b(2) * kc(8)
  int kc = bid & 7, b = bid >> 3;
  int t = threadIdx.x, lane = t & 63, w = t >> 6;
  int li = lane & 15, lgp = lane >> 4;
  int r = w >> 2, c = w & 3;
  f32x4 acc[8][4];
  for (int i = 0; i < 8; i++) for (int j = 0; j < 4; j++) acc[i][j] = (f32x4){0,0,0,0};
  for (int kk = 0; kk < 8; kk++){
    bf16x8 Bf[4];
    for (int j = 0; j < 4; j++)
      Bf[j] = *(const bf16x8*)(WoT + (size_t)(c*64 + j*16 + li)*2048 + kc*256 + kk*32 + lgp*8);
    for (int i = 0; i < 8; i++){
      bf16x8 Af = *(const bf16x8*)(Eb + (size_t)b*524288 + (size_t)(r*128 + i*16 + li)*2048 + kc*256 + kk*32 + lgp*8);
      for (int j = 0; j < 4; j++)
        acc[i][j] = __builtin_amdgcn_mfma_f32_16x16x32_bf16(Af, Bf[j], acc[i][j], 0, 0, 0);
    }
  }
  // C row=d (A rows), col=do (B rows): atomic into Facc[b][do][d]
  for (int i = 0; i < 8; i++)
    for (int j = 0; j < 4; j++){
      int dod = c*64 + j*16 + li;
      int dd = r*128 + i*16 + lgp*4;
      float* p = Facc + (size_t)b*65536 + (size_t)dod*256 + dd;
      atomicAdd(p + 0, acc[i][j][0]);
      atomicAdd(p + 1, acc[i][j][1]);
      atomicAdd(p + 2, acc[i][j][2]);
      atomicAdd(p + 3, acc[i][j][3]);
    }
  if (t < 256){
    float s = (kc == 0) ? bo[t] : 0.f;
    const unsigned short* wrow = WoT + (size_t)t*2048 + kc*256;
    const float* qrow = qbAll + (size_t)b*2048 + kc*256;
    for (int k8 = 0; k8 < 256; k8 += 8){
      bf16x8 v = *(const bf16x8*)(wrow + k8);
      for (int e = 0; e < 8; e++) s += bf2f((unsigned short)v[e]) * qrow[k8 + e];
    }
    atomicAdd(c0acc + (size_t)b*256 + t, s);
  }
}

// =============== out[tok][do] = x @ F + c0 (f32 direct) ===============
__global__ __launch_bounds__(512) void k_final2(const float* __restrict__ Facc,
                                                const unsigned short* __restrict__ xb,
                                                const float* __restrict__ c0acc,
                                                float* __restrict__ out){
  int bid = blockIdx.x;                        // 64 = b(2) * tc(32), 64 tokens each
  int tc = bid & 31, b = bid >> 5;
  int t = threadIdx.x, lane = t & 63, w = t >> 6;
  int li = lane & 15, lgp = lane >> 4;
  int r = w >> 1, c = w & 1;                   // r: do 4x64, c: tok 2x32
  int tok0 = b * 2048 + tc * 64;
  f32x4 acc[4][2];
  for (int i = 0; i < 4; i++) for (int j = 0; j < 2; j++) acc[i][j] = (f32x4){0,0,0,0};
  for (int kk = 0; kk < 8; kk++){
    bf16x8 Bf[2];
    for (int j = 0; j < 2; j++)
      Bf[j] = *(const bf16x8*)(xb + (size_t)(tok0 + c*32 + j*16 + li)*256 + kk*32 + lgp*8);
    for (int i = 0; i < 4; i++){
      const float* Fp = Facc + (size_t)b*65536 + (size_t)(r*64 + i*16 + li)*256 + kk*32 + lgp*8;
      f32x4 fa = *(const f32x4*)(Fp);
      f32x4 fb = *(const f32x4*)(Fp + 4);
      union { unsigned long long q[2]; bf16x8 v; } af;
      af.q[0] = pk4(fa[0], fa[1], fa[2], fa[3]);
      af.q[1] = pk4(fb[0], fb[1], fb[2], fb[3]);
      for (int j = 0; j < 2; j++)
        acc[i][j] = __builtin_amdgcn_mfma_f32_16x16x32_bf16(af.v, Bf[j], acc[i][j], 0, 0, 0);
    }
  }
  // C row=do, col=tok: direct f32x4 stores (sector-complete per wave)
  for (int i = 0; i < 4; i++){
    int dol = r*64 + i*16 + lgp*4;
    f32x4 c4 = *(const f32x4*)(c0acc + (size_t)b*256 + dol);
    for (int j = 0; j < 2; j++){
      int tokl = c*32 + j*16 + li;
      f32x4 v = acc[i][j];
      v[0] += c4[0]; v[1] += c4[1]; v[2] += c4[2]; v[3] += c4[3];
      *(f32x4*)(out + (size_t)(tok0 + tokl)*256 + dol) = v;
    }
  }
}

extern "C" void kernel_launch(void* const* d_in, const int* in_sizes, int n_in,
                              void* d_out, int out_size, void* d_ws, size_t ws_size,
                              hipStream_t stream) {
  const float* x     = (const float*)d_in[0];
  const float* Wq    = (const float*)d_in[1];
  const float* bq    = (const float*)d_in[2];
  const float* Wr    = (const float*)d_in[3];
  const float* br    = (const float*)d_in[4];
  const float* Wk    = (const float*)d_in[5];
  const float* bk    = (const float*)d_in[6];
  const float* Wv    = (const float*)d_in[7];
  const float* bv    = (const float*)d_in[8];
  const float* Wo    = (const float*)d_in[9];
  const float* bo    = (const float*)d_in[10];
  const float* bias0 = (const float*)d_in[11];
  float* out = (float*)d_out;

  char* ws = (char*)d_ws;
  size_t off = 0;
  auto alloc = [&](size_t bytes) -> char* {
    char* p = ws + off;
    off = (off + bytes + 255) & ~(size_t)255;
    return p;
  };
  unsigned short* xb   = (unsigned short*)alloc((size_t)4096 * 256 * 2);      // 2 MB
  unsigned short* xT   = (unsigned short*)alloc((size_t)2 * 256 * 2048 * 2);  // 2 MB
  unsigned short* Wqb  = (unsigned short*)alloc((size_t)256 * 2048 * 2);      // 1 MB
  unsigned short* WkT  = (unsigned short*)alloc((size_t)8 * 2048 * 256 * 2);  // 8 MB
  unsigned short* WvT  = (unsigned short*)alloc((size_t)8 * 2048 * 256 * 2);  // 8 MB
  unsigned short* WoT  = (unsigned short*)alloc((size_t)256 * 2048 * 2);      // 1 MB
  float*          routT= (float*)alloc((size_t)16 * 2048 * 4);                // 128 KB
  float*          u    = (float*)alloc((size_t)16 * 256 * 4);
  float*          rho  = (float*)alloc((size_t)16 * 4);
  float*          ku_g = (float*)alloc((size_t)16 * 2048 * 4);
  float*          vu_g = (float*)alloc((size_t)16 * 2048 * 4);
  unsigned short* Gp   = (unsigned short*)alloc((size_t)16 * 8 * 65536 * 2);  // 16 MB
  unsigned short* G    = (unsigned short*)alloc((size_t)16 * 65536 * 2);      // 2 MB
  unsigned short* memT = (unsigned short*)alloc((size_t)16 * 65536 * 2);      // 2 MB
  unsigned short* Eb   = (unsigned short*)alloc((size_t)2 * 256 * 2048 * 2);  // 2 MB
  float*          qbAll= (float*)alloc((size_t)2 * 2048 * 4);
  float*          Facc = (float*)alloc((size_t)(2 * 65536 + 2 * 256) * 4);    // F + c0 contiguous
  float*          c0acc= Facc + 2 * 65536;
  unsigned short* mempart = Gp;   // Gp dead after k_gred
  (void)ws_size; (void)in_sizes; (void)n_in; (void)out_size;

  hipMemsetAsync(Facc, 0, (size_t)(2 * 65536 + 2 * 256) * 4, stream);
  k_prep<<<10112, 256, 0, stream>>>(x, Wq, Wr, br, Wk, Wv, Wo, bias0,
                                    WkT, WvT, WoT, Wqb, xb, xT, routT);
  k_usum<<<16, 256, 0, stream>>>(xT, routT, u, rho);
  k_bias<<<128, 256, 0, stream>>>(WkT, WvT, u, ku_g, vu_g);
  k_gpart<<<128, 512, 0, stream>>>(xT, routT, Gp);
  k_gred<<<512, 256, 0, stream>>>(Gp, G);
  k_memh<<<256, 512, 0, stream>>>(G, WkT, WvT, bk, bv, ku_g, vu_g, rho, mempart);
  k_mred<<<512, 256, 0, stream>>>(mempart, memT);
  k_emat<<<32, 512, 0, stream>>>(memT, Wqb, bq, Eb, qbAll);
  k_fmat<<<16, 512, 0, stream>>>(Eb, WoT, qbAll, bo, Facc, c0acc);
  k_final2<<<64, 512, 0, stream>>>(Facc, xb, c0acc, out);
}

// Round 4
// 240.786 us; speedup vs baseline: 1.2586x; 1.1716x over previous
//
#include <hip/hip_runtime.h>

typedef __attribute__((ext_vector_type(8))) short bf16x8;
typedef __attribute__((ext_vector_type(4))) float f32x4;

#define DEV static __device__ __forceinline__

DEV unsigned short f2bf(float f){
  union { float f; unsigned u; } v; v.f = f;
  unsigned r = v.u + 0x7fffu + ((v.u >> 16) & 1u);
  return (unsigned short)(r >> 16);
}
DEV float bf2f(unsigned short u){
  union { unsigned u; float f; } v; v.u = ((unsigned)u) << 16;
  return v.f;
}
DEV unsigned long long pk4(float a, float b, float c, float d){
  unsigned lo = (unsigned)f2bf(a) | ((unsigned)f2bf(b) << 16);
  unsigned hi = (unsigned)f2bf(c) | ((unsigned)f2bf(d) << 16);
  return ((unsigned long long)hi << 32) | lo;
}

// =============== fused prep: weight transposes/converts + x prep + router ===============
__global__ __launch_bounds__(256) void k_prep(const float* __restrict__ x,
                                              const float* __restrict__ Wq,
                                              const float* __restrict__ Wr,
                                              const float* __restrict__ br,
                                              const float* __restrict__ Wk,
                                              const float* __restrict__ Wv,
                                              const float* __restrict__ Wo,
                                              const float* __restrict__ bias0,
                                              unsigned short* __restrict__ WkT,
                                              unsigned short* __restrict__ WvT,
                                              unsigned short* __restrict__ WoT,
                                              unsigned short* __restrict__ Wqb,
                                              unsigned short* __restrict__ xb,
                                              unsigned short* __restrict__ xT,
                                              float* __restrict__ routT){
  __shared__ float tile[32*33];
  __shared__ float lg[32][8];
  __shared__ float rt2[32][8];
  int bid = blockIdx.x;
  int t = threadIdx.x;
  int tx = t & 31, ty = t >> 5;

  if (bid < 8192){                      // Wk (0..4095) / Wv (4096..8191): [8][256][2048] -> [8][2048][256]
    const float* src = (bid < 4096) ? Wk : Wv;
    unsigned short* dst = (bid < 4096) ? WkT : WvT;
    int q = bid & 4095;
    int bat = q >> 9, rem = q & 511;
    int c0 = (rem >> 3) * 32, r0 = (rem & 7) * 32;
    size_t boff = (size_t)bat * 256 * 2048;
    for (int i = 0; i < 4; i++)
      tile[(ty + i*8)*33 + tx] = src[boff + (size_t)(r0 + ty + i*8) * 2048 + c0 + tx];
    __syncthreads();
    for (int i = 0; i < 4; i++)
      dst[boff + (size_t)(c0 + ty + i*8) * 256 + r0 + tx] = f2bf(tile[tx*33 + ty + i*8]);
  } else if (bid < 8704){               // Wo: [2048][256] -> [256][2048]
    int q = bid - 8192;
    int c0 = (q >> 6) * 32, r0 = (q & 63) * 32;
    for (int i = 0; i < 4; i++)
      tile[(ty + i*8)*33 + tx] = Wo[(size_t)(r0 + ty + i*8) * 256 + c0 + tx];
    __syncthreads();
    for (int i = 0; i < 4; i++)
      WoT[(size_t)(c0 + ty + i*8) * 2048 + r0 + tx] = f2bf(tile[tx*33 + ty + i*8]);
  } else if (bid < 8960){               // Wq plain convert [256][2048]
    int q = bid - 8704;
    size_t idx = (size_t)q * 2048 + t * 8;
    f32x4 a = *(const f32x4*)(Wq + idx);
    f32x4 b = *(const f32x4*)(Wq + idx + 4);
    *(unsigned long long*)(Wqb + idx)     = pk4(a[0], a[1], a[2], a[3]);
    *(unsigned long long*)(Wqb + idx + 4) = pk4(b[0], b[1], b[2], b[3]);
  } else if (bid < 9984){               // x: [2][2048][256] -> xb [4096][256] + xT [2][256][2048]
    int q = bid - 8960;
    int bat = q >> 9, rem = q & 511;
    int c0 = (rem >> 6) * 32, r0 = (rem & 63) * 32;
    size_t boff = (size_t)bat * 2048 * 256;
    for (int i = 0; i < 4; i++){
      float v = x[boff + (size_t)(r0 + ty + i*8) * 256 + c0 + tx];
      tile[(ty + i*8)*33 + tx] = v;
      xb[boff + (size_t)(r0 + ty + i*8) * 256 + c0 + tx] = f2bf(v);
    }
    __syncthreads();
    for (int i = 0; i < 4; i++)
      xT[(size_t)(bat*256 + c0 + ty + i*8) * 2048 + r0 + tx] = f2bf(tile[tx*33 + ty + i*8]);
  } else {                              // router: 128 blocks, 32 tokens each
    int row = t >> 3, mm = t & 7;
    int n = (bid - 9984) * 32 + row;
    const float* xr = x + (size_t)n * 256;
    float acc = 0.f;
    for (int d = 0; d < 256; d++) acc += xr[d] * Wr[d * 8 + mm];
    acc += br[mm];
    lg[row][mm] = acc;
    __syncthreads();
    if (t < 32){
      int r = t; int n2 = (bid - 9984) * 32 + r; int b = n2 >> 11;
      float mx = -1e30f;
      for (int i = 0; i < 8; i++) mx = fmaxf(mx, lg[r][i]);
      float s[8]; float sum = 0.f;
      for (int i = 0; i < 8; i++){ s[i] = __expf(lg[r][i] - mx); sum += s[i]; }
      for (int i = 0; i < 8; i++) s[i] /= sum;
      float bb[8];
      for (int i = 0; i < 8; i++) bb[i] = s[i] + bias0[b * 8 + i];
      int i1 = 0;
      for (int i = 1; i < 8; i++) if (bb[i] > bb[i1]) i1 = i;
      int i2 = -1;
      for (int i = 0; i < 8; i++){ if (i == i1) continue; if (i2 < 0 || bb[i] > bb[i2]) i2 = i; }
      float wsum = s[i1] + s[i2];
      for (int i = 0; i < 8; i++)
        rt2[r][i] = (i == i1) ? s[i1] / wsum : ((i == i2) ? s[i2] / wsum : 0.f);
    }
    __syncthreads();
    int n3 = (bid - 9984) * 32 + row;
    int b = n3 >> 11, sl = n3 & 2047;
    routT[((size_t)b * 8 + mm) * 2048 + sl] = rt2[row][mm];
  }
}

// =============== u[bm][d] += sum_{s in chunk} r*x ; rho[bm] += sum r  (atomic, skip r==0) ===============
__global__ __launch_bounds__(256) void k_usum(const unsigned short* __restrict__ xb,
                                              const float* __restrict__ routT,
                                              float* __restrict__ u, float* __restrict__ rho){
  __shared__ float rl[128];
  int bid = blockIdx.x;                 // 256 = bm(16) * sc(16)
  int sc = bid & 15, bm = bid >> 4, b = bm >> 3;
  int t = threadIdx.x;
  int s0 = sc * 128;
  if (t < 128) rl[t] = routT[(size_t)bm * 2048 + s0 + t];
  __syncthreads();
  float acc = 0.f;
  const unsigned short* xrow = xb + ((size_t)(b * 2048 + s0)) * 256 + t;
  for (int s = 0; s < 128; s++){
    float rv = rl[s];
    if (rv != 0.f)
      acc += rv * bf2f(xrow[(size_t)s * 256]);
  }
  atomicAdd(u + (size_t)bm * 256 + t, acc);
  if (t == 0){
    float rs = 0.f;
    for (int s = 0; s < 128; s++) rs += rl[s];
    atomicAdd(rho + bm, rs);
  }
}

// =============== ku/vu = WkT/WvT . u ===============
__global__ __launch_bounds__(256) void k_bias(const unsigned short* __restrict__ WkT,
                                              const unsigned short* __restrict__ WvT,
                                              const float* __restrict__ u,
                                              float* __restrict__ ku_g, float* __restrict__ vu_g){
  __shared__ float uL[256];
  int bid = blockIdx.x, t = threadIdx.x;
  int bm = bid >> 3, hseg = bid & 7, m = bm & 7;
  if (t < 64) *(f32x4*)(uL + t*4) = *(const f32x4*)(u + (size_t)bm*256 + t*4);
  __syncthreads();
  int hd = hseg * 256 + t;
  const unsigned short* wk = WkT + ((size_t)m*2048 + hd) * 256;
  const unsigned short* wv = WvT + ((size_t)m*2048 + hd) * 256;
  float sk = 0.f, sv = 0.f;
  for (int d8 = 0; d8 < 256; d8 += 8){
    bf16x8 a = *(const bf16x8*)(wk + d8);
    bf16x8 c = *(const bf16x8*)(wv + d8);
    for (int j = 0; j < 8; j++){
      sk += bf2f((unsigned short)a[j]) * uL[d8+j];
      sv += bf2f((unsigned short)c[j]) * uL[d8+j];
    }
  }
  ku_g[(size_t)bm*2048 + hd] = sk;
  vu_g[(size_t)bm*2048 + hd] = sv;
}

// =============== Gp[bm][kc] = X_chunk^T diag(r) X_chunk (256x256, K=256 tokens) ===============
__global__ __launch_bounds__(512) void k_gpart(const unsigned short* __restrict__ xT,
                                               const float* __restrict__ routT,
                                               unsigned short* __restrict__ Gp){
  __shared__ unsigned short As[256*72];     // scaled, 36 KB
  __shared__ unsigned short Bs[256*72];     // unscaled, 36 KB
  __shared__ float rl[64];
  int bid = blockIdx.x;                      // 128 = b(2) m(8) kc(8)
  int kc = bid & 7, m = (bid >> 3) & 7, b = bid >> 6;
  int bm = b * 8 + m;
  int t = threadIdx.x, lane = t & 63, w = t >> 6;
  int li = lane & 15, lgp = lane >> 4;
  int p = w >> 2, q = w & 3;
  f32x4 acc[8][4];
  for (int i = 0; i < 8; i++) for (int j = 0; j < 4; j++) acc[i][j] = (f32x4){0,0,0,0};
  for (int c4 = 0; c4 < 4; c4++){
    int s0 = kc * 256 + c4 * 64;
    if (t < 64) rl[t] = routT[(size_t)bm*2048 + s0 + t];
    __syncthreads();
    for (int qq = 0; qq < 4; qq++){
      int idx = t + qq*512;
      int row = idx >> 3, sc = (idx & 7) * 8;
      bf16x8 xv = *(const bf16x8*)(xT + ((size_t)(b*256 + row))*2048 + s0 + sc);
      *(bf16x8*)(&Bs[row*72 + sc]) = xv;
      f32x4 r0 = *(const f32x4*)(rl + sc);
      f32x4 r1 = *(const f32x4*)(rl + sc + 4);
      bf16x8 sv;
      sv[0]=(short)f2bf(bf2f((unsigned short)xv[0])*r0[0]);
      sv[1]=(short)f2bf(bf2f((unsigned short)xv[1])*r0[1]);
      sv[2]=(short)f2bf(bf2f((unsigned short)xv[2])*r0[2]);
      sv[3]=(short)f2bf(bf2f((unsigned short)xv[3])*r0[3]);
      sv[4]=(short)f2bf(bf2f((unsigned short)xv[4])*r1[0]);
      sv[5]=(short)f2bf(bf2f((unsigned short)xv[5])*r1[1]);
      sv[6]=(short)f2bf(bf2f((unsigned short)xv[6])*r1[2]);
      sv[7]=(short)f2bf(bf2f((unsigned short)xv[7])*r1[3]);
      *(bf16x8*)(&As[row*72 + sc]) = sv;
    }
    __syncthreads();
    for (int kk = 0; kk < 2; kk++){
      bf16x8 Bf[4];
      for (int j = 0; j < 4; j++)
        Bf[j] = *(const bf16x8*)(&Bs[(q*64 + j*16 + li)*72 + kk*32 + lgp*8]);
      for (int i = 0; i < 8; i++){
        bf16x8 Af = *(const bf16x8*)(&As[(p*128 + i*16 + li)*72 + kk*32 + lgp*8]);
        for (int j = 0; j < 4; j++)
          acc[i][j] = __builtin_amdgcn_mfma_f32_16x16x32_bf16(Af, Bf[j], acc[i][j], 0, 0, 0);
      }
    }
    __syncthreads();
  }
  // bounce C (row=d1 from A, col=d2 from B) -> Gp[bm][kc][d2][d1]
  unsigned short* Cs = As;                   // 64 x 264 overlay
  for (int ph = 0; ph < 4; ph++){
    if (q == ph){
      for (int i = 0; i < 8; i++)
        for (int j = 0; j < 4; j++){
          int rr = j*16 + li, cc = p*128 + i*16 + lgp*4;
          *(unsigned long long*)(&Cs[rr*264 + cc]) =
            pk4(acc[i][j][0], acc[i][j][1], acc[i][j][2], acc[i][j][3]);
        }
    }
    __syncthreads();
    for (int qq = 0; qq < 4; qq++){
      int idx = t + qq*512;
      int row = idx >> 5, cc = (idx & 31) * 8;
      *(bf16x8*)(Gp + (((size_t)bm*8 + kc) << 16) + (size_t)(ph*64 + row)*256 + cc) =
        *(const bf16x8*)(&Cs[row*264 + cc]);
    }
    __syncthreads();
  }
}

// =============== reduce Gp over kc -> G[bm][256][256] ===============
__global__ __launch_bounds__(256) void k_gred(const unsigned short* __restrict__ Gp,
                                              unsigned short* __restrict__ G){
  int idx = blockIdx.x * 256 + threadIdx.x;
  int bm = idx >> 13; size_t e8 = (size_t)(idx & 8191) * 8;
  float s[8] = {0,0,0,0,0,0,0,0};
  for (int kc = 0; kc < 8; kc++){
    bf16x8 v = *(const bf16x8*)(Gp + (((size_t)bm*8 + kc) << 16) + e8);
    for (int j = 0; j < 8; j++) s[j] += bf2f((unsigned short)v[j]);
  }
  *(unsigned long long*)(G + ((size_t)bm << 16) + e8)     = pk4(s[0], s[1], s[2], s[3]);
  *(unsigned long long*)(G + ((size_t)bm << 16) + e8 + 4) = pk4(s[4], s[5], s[6], s[7]);
}

// =============== per (b,m,h,vh): T = G@Wv (LDS), mem_part = Wk^T@T + rank-1 ===============
__global__ __launch_bounds__(512) void k_memh(const unsigned short* __restrict__ G,
                                              const unsigned short* __restrict__ WkT,
                                              const unsigned short* __restrict__ WvT,
                                              const float* __restrict__ bk,
                                              const float* __restrict__ bv,
                                              const float* __restrict__ ku_g,
                                              const float* __restrict__ vu_g,
                                              const float* __restrict__ rho,
                                              unsigned short* __restrict__ mempart){
  __shared__ unsigned short TT[128*256];     // 64 KB, XOR-swizzled [vd][d1]
  int bid = blockIdx.x;                       // 256 = b(2) m(8) h(8) vq(2)
  int vq = bid & 1, h = (bid >> 1) & 7, m = (bid >> 4) & 7, b = bid >> 7;
  int bm = b * 8 + m, bh = b * 8 + h;
  int hd0 = h * 256, vd0 = vq * 128;
  int t = threadIdx.x, lane = t & 63, w = t >> 6;
  int li = lane & 15, lgp = lane >> 4;
  int r = w >> 2, c = w & 3;
  // stage 1: T[d1 256][vd 128] = G @ Wv_slice
  f32x4 a1[8][2];
  for (int i = 0; i < 8; i++) for (int j = 0; j < 2; j++) a1[i][j] = (f32x4){0,0,0,0};
  for (int kk = 0; kk < 8; kk++){
    bf16x8 Bf[2];
    for (int j = 0; j < 2; j++)
      Bf[j] = *(const bf16x8*)(WvT + ((size_t)m*2048 + hd0 + vd0 + c*32 + j*16 + li)*256 + kk*32 + lgp*8);
    for (int i = 0; i < 8; i++){
      bf16x8 Af = *(const bf16x8*)(G + ((size_t)bm << 16) + (size_t)(r*128 + i*16 + li)*256 + kk*32 + lgp*8);
      for (int j = 0; j < 2; j++)
        a1[i][j] = __builtin_amdgcn_mfma_f32_16x16x32_bf16(Af, Bf[j], a1[i][j], 0, 0, 0);
    }
  }
  for (int i = 0; i < 8; i++)
    for (int j = 0; j < 2; j++){
      int vdl = c*32 + j*16 + li;
      int d1 = r*128 + i*16 + lgp*4;
      int bo2 = (vdl*512 + d1*2) ^ ((vdl & 7) << 4);
      *(unsigned long long*)((char*)TT + bo2) = pk4(a1[i][j][0], a1[i][j][1], a1[i][j][2], a1[i][j][3]);
    }
  __syncthreads();
  // stage 2: mem[kd 256][vd 128] = Wk^T @ T
  f32x4 a2[8][2];
  for (int i = 0; i < 8; i++) for (int j = 0; j < 2; j++) a2[i][j] = (f32x4){0,0,0,0};
  for (int kk = 0; kk < 8; kk++){
    bf16x8 Bf[2];
    for (int j = 0; j < 2; j++){
      int vdl = c*32 + j*16 + li;
      int bo2 = (vdl*512 + (kk*32 + lgp*8)*2) ^ ((vdl & 7) << 4);
      Bf[j] = *(const bf16x8*)((char*)TT + bo2);
    }
    for (int i = 0; i < 8; i++){
      bf16x8 Af = *(const bf16x8*)(WkT + ((size_t)m*2048 + hd0 + r*128 + i*16 + li)*256 + kk*32 + lgp*8);
      for (int j = 0; j < 2; j++)
        a2[i][j] = __builtin_amdgcn_mfma_f32_16x16x32_bf16(Af, Bf[j], a2[i][j], 0, 0, 0);
    }
  }
  __syncthreads();
  // epilogue (rank-1 bias terms) + coalescing bounce
  float rhov = rho[bm];
  unsigned short* Cs = TT;                    // 32 x 264 overlay
  for (int ph = 0; ph < 4; ph++){
    if (c == ph){
      for (int j = 0; j < 2; j++){
        int vdl = c*32 + j*16 + li;
        int vdg = hd0 + vd0 + vdl;
        float bvv = bv[(size_t)m*2048 + vdg];
        float vuv = vu_g[(size_t)bm*2048 + vdg];
        float bb = vuv + rhov * bvv;
        for (int i = 0; i < 8; i++){
          int kd = r*128 + i*16 + lgp*4;
          f32x4 ku4 = *(const f32x4*)(ku_g + (size_t)bm*2048 + hd0 + kd);
          f32x4 bk4 = *(const f32x4*)(bk + (size_t)m*2048 + hd0 + kd);
          float v0 = a2[i][j][0] + ku4[0]*bvv + bk4[0]*bb;
          float v1 = a2[i][j][1] + ku4[1]*bvv + bk4[1]*bb;
          float v2 = a2[i][j][2] + ku4[2]*bvv + bk4[2]*bb;
          float v3 = a2[i][j][3] + ku4[3]*bvv + bk4[3]*bb;
          *(unsigned long long*)(&Cs[(j*16 + li)*264 + kd]) = pk4(v0, v1, v2, v3);
        }
      }
    }
    __syncthreads();
    for (int qq = 0; qq < 2; qq++){
      int idx = t + qq*512;
      int row = idx >> 5, cc = (idx & 31) * 8;
      *(bf16x8*)(mempart + ((size_t)((bh*2 + vq)*8 + m))*32768 + (size_t)(ph*32 + row)*256 + cc) =
        *(const bf16x8*)(&Cs[row*264 + cc]);
    }
    __syncthreads();
  }
}

// =============== reduce mempart over m -> memT[bh][vd][kd] ===============
__global__ __launch_bounds__(256) void k_mred(const unsigned short* __restrict__ mempart,
                                              unsigned short* __restrict__ memT){
  int idx = blockIdx.x * 256 + threadIdx.x;   // 131072
  int bh = idx >> 13; int rem = idx & 8191;
  int vd = rem >> 5, kd0 = (rem & 31) * 8;
  int vq = vd >> 7, vdl = vd & 127;
  size_t src = ((size_t)((bh*2 + vq)*8))*32768 + (size_t)vdl*256 + kd0;
  float s[8] = {0,0,0,0,0,0,0,0};
  for (int m = 0; m < 8; m++){
    bf16x8 v = *(const bf16x8*)(mempart + src + (size_t)m*32768);
    for (int j = 0; j < 8; j++) s[j] += bf2f((unsigned short)v[j]);
  }
  size_t dst = (size_t)bh*65536 + (size_t)vd*256 + kd0;
  *(unsigned long long*)(memT + dst)     = pk4(s[0], s[1], s[2], s[3]);
  *(unsigned long long*)(memT + dst + 4) = pk4(s[4], s[5], s[6], s[7]);
}

// =============== E_h = Wq_h @ mem_h  -> Eb[b][d][h*256+vd]; qbAll = bq_h . mem_h ===============
__global__ __launch_bounds__(512) void k_emat(const unsigned short* __restrict__ memT,
                                              const unsigned short* __restrict__ Wqb,
                                              const float* __restrict__ bq,
                                              unsigned short* __restrict__ Eb,
                                              float* __restrict__ qbAll){
  __shared__ unsigned short Cs[32*264];
  int bid = blockIdx.x;                        // 32 = bh(16) * dseg(2)
  int dseg = bid & 1, bh = bid >> 1;
  int b = bh >> 3, h = bh & 7;
  int hd0 = h * 256, d0 = dseg * 128;
  int t = threadIdx.x, lane = t & 63, w = t >> 6;
  int li = lane & 15, lgp = lane >> 4;
  int r = w >> 2, c = w & 3;
  // out [vd 256][d 128]: A = memT rows vd, B = Wqb rows d (K = kd 256)
  f32x4 acc[8][2];
  for (int i = 0; i < 8; i++) for (int j = 0; j < 2; j++) acc[i][j] = (f32x4){0,0,0,0};
  for (int kk = 0; kk < 8; kk++){
    bf16x8 Bf[2];
    for (int j = 0; j < 2; j++)
      Bf[j] = *(const bf16x8*)(Wqb + (size_t)(d0 + c*32 + j*16 + li)*2048 + hd0 + kk*32 + lgp*8);
    for (int i = 0; i < 8; i++){
      bf16x8 Af = *(const bf16x8*)(memT + (size_t)bh*65536 + (size_t)(r*128 + i*16 + li)*256 + kk*32 + lgp*8);
      for (int j = 0; j < 2; j++)
        acc[i][j] = __builtin_amdgcn_mfma_f32_16x16x32_bf16(Af, Bf[j], acc[i][j], 0, 0, 0);
    }
  }
  // qb: qbAll[b][hd0+vd] = sum_kd bq[hd0+kd]*mem[kd][vd]
  if (dseg == 0 && t < 256){
    const unsigned short* mrow = memT + (size_t)bh*65536 + (size_t)t*256;
    float s = 0.f;
    for (int k8 = 0; k8 < 256; k8 += 8){
      bf16x8 v = *(const bf16x8*)(mrow + k8);
      for (int e = 0; e < 8; e++) s += bf2f((unsigned short)v[e]) * bq[hd0 + k8 + e];
    }
    qbAll[(size_t)b*2048 + hd0 + t] = s;
  }
  // bounce: C row=vd, col=d -> Eb[b][d][hd0+vd]
  for (int ph = 0; ph < 4; ph++){
    if (c == ph){
      for (int i = 0; i < 8; i++)
        for (int j = 0; j < 2; j++){
          int dl = j*16 + li;
          int vd4 = r*128 + i*16 + lgp*4;
          *(unsigned long long*)(&Cs[dl*264 + vd4]) =
            pk4(acc[i][j][0], acc[i][j][1], acc[i][j][2], acc[i][j][3]);
        }
    }
    __syncthreads();
    for (int qq = 0; qq < 2; qq++){
      int idx = t + qq*512;
      int row = idx >> 5, cc = (idx & 31) * 8;
      *(bf16x8*)(Eb + (size_t)b*524288 + (size_t)(d0 + ph*32 + row)*2048 + hd0 + cc) =
        *(const bf16x8*)(&Cs[row*264 + cc]);
    }
    __syncthreads();
  }
}

// =============== F += Eb @ WoT^T (split-K atomic, f32); c0 += qbAll.Wo + bo ===============
__global__ __launch_bounds__(512) void k_fmat(const unsigned short* __restrict__ Eb,
                                              const unsigned short* __restrict__ WoT,
                                              const float* __restrict__ qbAll,
                                              const float* __restrict__ bo,
                                              float* __restrict__ Facc,
                                              float* __restrict__ c0acc){
  int bid = blockIdx.x;                        // 16 = b(2) * kc(8)
  int kc = bid & 7, b = bid >> 3;
  int t = threadIdx.x, lane = t & 63, w = t >> 6;
  int li = lane & 15, lgp = lane >> 4;
  int r = w >> 2, c = w & 3;
  f32x4 acc[8][4];
  for (int i = 0; i < 8; i++) for (int j = 0; j < 4; j++) acc[i][j] = (f32x4){0,0,0,0};
  for (int kk = 0; kk < 8; kk++){
    bf16x8 Bf[4];
    for (int j = 0; j < 4; j++)
      Bf[j] = *(const bf16x8*)(WoT + (size_t)(c*64 + j*16 + li)*2048 + kc*256 + kk*32 + lgp*8);
    for (int i = 0; i < 8; i++){
      bf16x8 Af = *(const bf16x8*)(Eb + (size_t)b*524288 + (size_t)(r*128 + i*16 + li)*2048 + kc*256 + kk*32 + lgp*8);
      for (int j = 0; j < 4; j++)
        acc[i][j] = __builtin_amdgcn_mfma_f32_16x16x32_bf16(Af, Bf[j], acc[i][j], 0, 0, 0);
    }
  }
  // C row=d (A rows), col=do (B rows): atomic into Facc[b][do][d]
  for (int i = 0; i < 8; i++)
    for (int j = 0; j < 4; j++){
      int dod = c*64 + j*16 + li;
      int dd = r*128 + i*16 + lgp*4;
      float* p = Facc + (size_t)b*65536 + (size_t)dod*256 + dd;
      atomicAdd(p + 0, acc[i][j][0]);
      atomicAdd(p + 1, acc[i][j][1]);
      atomicAdd(p + 2, acc[i][j][2]);
      atomicAdd(p + 3, acc[i][j][3]);
    }
  if (t < 256){
    float s = (kc == 0) ? bo[t] : 0.f;
    const unsigned short* wrow = WoT + (size_t)t*2048 + kc*256;
    const float* qrow = qbAll + (size_t)b*2048 + kc*256;
    for (int k8 = 0; k8 < 256; k8 += 8){
      bf16x8 v = *(const bf16x8*)(wrow + k8);
      for (int e = 0; e < 8; e++) s += bf2f((unsigned short)v[e]) * qrow[k8 + e];
    }
    atomicAdd(c0acc + (size_t)b*256 + t, s);
  }
}

// =============== out[tok][do] = x @ F + c0 (f32 direct) ===============
__global__ __launch_bounds__(512) void k_final2(const float* __restrict__ Facc,
                                                const unsigned short* __restrict__ xb,
                                                const float* __restrict__ c0acc,
                                                float* __restrict__ out){
  int bid = blockIdx.x;                        // 64 = b(2) * tc(32), 64 tokens each
  int tc = bid & 31, b = bid >> 5;
  int t = threadIdx.x, lane = t & 63, w = t >> 6;
  int li = lane & 15, lgp = lane >> 4;
  int r = w >> 1, c = w & 1;                   // r: do 4x64, c: tok 2x32
  int tok0 = b * 2048 + tc * 64;
  f32x4 acc[4][2];
  for (int i = 0; i < 4; i++) for (int j = 0; j < 2; j++) acc[i][j] = (f32x4){0,0,0,0};
  for (int kk = 0; kk < 8; kk++){
    bf16x8 Bf[2];
    for (int j = 0; j < 2; j++)
      Bf[j] = *(const bf16x8*)(xb + (size_t)(tok0 + c*32 + j*16 + li)*256 + kk*32 + lgp*8);
    for (int i = 0; i < 4; i++){
      const float* Fp = Facc + (size_t)b*65536 + (size_t)(r*64 + i*16 + li)*256 + kk*32 + lgp*8;
      f32x4 fa = *(const f32x4*)(Fp);
      f32x4 fb = *(const f32x4*)(Fp + 4);
      union { unsigned long long q[2]; bf16x8 v; } af;
      af.q[0] = pk4(fa[0], fa[1], fa[2], fa[3]);
      af.q[1] = pk4(fb[0], fb[1], fb[2], fb[3]);
      for (int j = 0; j < 2; j++)
        acc[i][j] = __builtin_amdgcn_mfma_f32_16x16x32_bf16(af.v, Bf[j], acc[i][j], 0, 0, 0);
    }
  }
  // C row=do, col=tok: direct f32x4 stores (sector-complete per wave)
  for (int i = 0; i < 4; i++){
    int dol = r*64 + i*16 + lgp*4;
    f32x4 c4 = *(const f32x4*)(c0acc + (size_t)b*256 + dol);
    for (int j = 0; j < 2; j++){
      int tokl = c*32 + j*16 + li;
      f32x4 v = acc[i][j];
      v[0] += c4[0]; v[1] += c4[1]; v[2] += c4[2]; v[3] += c4[3];
      *(f32x4*)(out + (size_t)(tok0 + tokl)*256 + dol) = v;
    }
  }
}

extern "C" void kernel_launch(void* const* d_in, const int* in_sizes, int n_in,
                              void* d_out, int out_size, void* d_ws, size_t ws_size,
                              hipStream_t stream) {
  const float* x     = (const float*)d_in[0];
  const float* Wq    = (const float*)d_in[1];
  const float* bq    = (const float*)d_in[2];
  const float* Wr    = (const float*)d_in[3];
  const float* br    = (const float*)d_in[4];
  const float* Wk    = (const float*)d_in[5];
  const float* bk    = (const float*)d_in[6];
  const float* Wv    = (const float*)d_in[7];
  const float* bv    = (const float*)d_in[8];
  const float* Wo    = (const float*)d_in[9];
  const float* bo    = (const float*)d_in[10];
  const float* bias0 = (const float*)d_in[11];
  float* out = (float*)d_out;

  char* ws = (char*)d_ws;
  size_t off = 0;
  auto alloc = [&](size_t bytes) -> char* {
    char* p = ws + off;
    off = (off + bytes + 255) & ~(size_t)255;
    return p;
  };
  unsigned short* xb   = (unsigned short*)alloc((size_t)4096 * 256 * 2);      // 2 MB
  unsigned short* xT   = (unsigned short*)alloc((size_t)2 * 256 * 2048 * 2);  // 2 MB
  unsigned short* Wqb  = (unsigned short*)alloc((size_t)256 * 2048 * 2);      // 1 MB
  unsigned short* WkT  = (unsigned short*)alloc((size_t)8 * 2048 * 256 * 2);  // 8 MB
  unsigned short* WvT  = (unsigned short*)alloc((size_t)8 * 2048 * 256 * 2);  // 8 MB
  unsigned short* WoT  = (unsigned short*)alloc((size_t)256 * 2048 * 2);      // 1 MB
  float*          routT= (float*)alloc((size_t)16 * 2048 * 4);                // 128 KB
  float*          u    = (float*)alloc((size_t)16 * 256 * 4);                 // 16 KB
  float*          rho  = (float*)alloc((size_t)16 * 4);
  float*          ku_g = (float*)alloc((size_t)16 * 2048 * 4);
  float*          vu_g = (float*)alloc((size_t)16 * 2048 * 4);
  unsigned short* Gp   = (unsigned short*)alloc((size_t)16 * 8 * 65536 * 2);  // 16 MB
  unsigned short* G    = (unsigned short*)alloc((size_t)16 * 65536 * 2);      // 2 MB
  unsigned short* memT = (unsigned short*)alloc((size_t)16 * 65536 * 2);      // 2 MB
  unsigned short* Eb   = (unsigned short*)alloc((size_t)2 * 256 * 2048 * 2);  // 2 MB
  float*          qbAll= (float*)alloc((size_t)2 * 2048 * 4);
  float*          Facc = (float*)alloc((size_t)(2 * 65536 + 2 * 256) * 4);    // F + c0 contiguous
  float*          c0acc= Facc + 2 * 65536;
  unsigned short* mempart = Gp;   // Gp dead after k_gred
  (void)ws_size; (void)in_sizes; (void)n_in; (void)out_size;

  hipMemsetAsync(Facc, 0, (size_t)(2 * 65536 + 2 * 256) * 4, stream);
  hipMemsetAsync(u, 0, (size_t)16 * 256 * 4 + 256, stream);   // u + rho (contiguous allocs)
  k_prep<<<10112, 256, 0, stream>>>(x, Wq, Wr, br, Wk, Wv, Wo, bias0,
                                    WkT, WvT, WoT, Wqb, xb, xT, routT);
  k_usum<<<256, 256, 0, stream>>>(xb, routT, u, rho);
  k_bias<<<128, 256, 0, stream>>>(WkT, WvT, u, ku_g, vu_g);
  k_gpart<<<128, 512, 0, stream>>>(xT, routT, Gp);
  k_gred<<<512, 256, 0, stream>>>(Gp, G);
  k_memh<<<256, 512, 0, stream>>>(G, WkT, WvT, bk, bv, ku_g, vu_g, rho, mempart);
  k_mred<<<512, 256, 0, stream>>>(mempart, memT);
  k_emat<<<32, 512, 0, stream>>>(memT, Wqb, bq, Eb, qbAll);
  k_fmat<<<16, 512, 0, stream>>>(Eb, WoT, qbAll, bo, Facc, c0acc);
  k_final2<<<64, 512, 0, stream>>>(Facc, xb, c0acc, out);
}

// Round 5
// 234.842 us; speedup vs baseline: 1.2905x; 1.0253x over previous
//
#include <hip/hip_runtime.h>

typedef __attribute__((ext_vector_type(8))) short bf16x8;
typedef __attribute__((ext_vector_type(4))) float f32x4;

#define DEV static __device__ __forceinline__

DEV unsigned short f2bf(float f){
  union { float f; unsigned u; } v; v.f = f;
  unsigned r = v.u + 0x7fffu + ((v.u >> 16) & 1u);
  return (unsigned short)(r >> 16);
}
DEV float bf2f(unsigned short u){
  union { unsigned u; float f; } v; v.u = ((unsigned)u) << 16;
  return v.f;
}
DEV unsigned long long pk4(float a, float b, float c, float d){
  unsigned lo = (unsigned)f2bf(a) | ((unsigned)f2bf(b) << 16);
  unsigned hi = (unsigned)f2bf(c) | ((unsigned)f2bf(d) << 16);
  return ((unsigned long long)hi << 32) | lo;
}

// =============== fused prep: weight transposes/converts + x prep + router ===============
__global__ __launch_bounds__(256) void k_prep(const float* __restrict__ x,
                                              const float* __restrict__ Wq,
                                              const float* __restrict__ Wr,
                                              const float* __restrict__ br,
                                              const float* __restrict__ Wk,
                                              const float* __restrict__ Wv,
                                              const float* __restrict__ Wo,
                                              const float* __restrict__ bias0,
                                              unsigned short* __restrict__ WkT,
                                              unsigned short* __restrict__ WvT,
                                              unsigned short* __restrict__ WoT,
                                              unsigned short* __restrict__ Wqb,
                                              unsigned short* __restrict__ xb,
                                              unsigned short* __restrict__ xT,
                                              float* __restrict__ routT){
  __shared__ float tile[32*33];
  __shared__ float lg[32][8];
  __shared__ float rt2[32][8];
  int bid = blockIdx.x;
  int t = threadIdx.x;
  int tx = t & 31, ty = t >> 5;

  if (bid < 8192){                      // Wk (0..4095) / Wv (4096..8191): [8][256][2048] -> [8][2048][256]
    const float* src = (bid < 4096) ? Wk : Wv;
    unsigned short* dst = (bid < 4096) ? WkT : WvT;
    int q = bid & 4095;
    int bat = q >> 9, rem = q & 511;
    int c0 = (rem >> 3) * 32, r0 = (rem & 7) * 32;
    size_t boff = (size_t)bat * 256 * 2048;
    for (int i = 0; i < 4; i++)
      tile[(ty + i*8)*33 + tx] = src[boff + (size_t)(r0 + ty + i*8) * 2048 + c0 + tx];
    __syncthreads();
    for (int i = 0; i < 4; i++)
      dst[boff + (size_t)(c0 + ty + i*8) * 256 + r0 + tx] = f2bf(tile[tx*33 + ty + i*8]);
  } else if (bid < 8704){               // Wo: [2048][256] -> [256][2048]
    int q = bid - 8192;
    int c0 = (q >> 6) * 32, r0 = (q & 63) * 32;
    for (int i = 0; i < 4; i++)
      tile[(ty + i*8)*33 + tx] = Wo[(size_t)(r0 + ty + i*8) * 256 + c0 + tx];
    __syncthreads();
    for (int i = 0; i < 4; i++)
      WoT[(size_t)(c0 + ty + i*8) * 2048 + r0 + tx] = f2bf(tile[tx*33 + ty + i*8]);
  } else if (bid < 8960){               // Wq plain convert [256][2048]
    int q = bid - 8704;
    size_t idx = (size_t)q * 2048 + t * 8;
    f32x4 a = *(const f32x4*)(Wq + idx);
    f32x4 b = *(const f32x4*)(Wq + idx + 4);
    *(unsigned long long*)(Wqb + idx)     = pk4(a[0], a[1], a[2], a[3]);
    *(unsigned long long*)(Wqb + idx + 4) = pk4(b[0], b[1], b[2], b[3]);
  } else if (bid < 9984){               // x: [2][2048][256] -> xb [4096][256] + xT [2][256][2048]
    int q = bid - 8960;
    int bat = q >> 9, rem = q & 511;
    int c0 = (rem >> 6) * 32, r0 = (rem & 63) * 32;
    size_t boff = (size_t)bat * 2048 * 256;
    for (int i = 0; i < 4; i++){
      float v = x[boff + (size_t)(r0 + ty + i*8) * 256 + c0 + tx];
      tile[(ty + i*8)*33 + tx] = v;
      xb[boff + (size_t)(r0 + ty + i*8) * 256 + c0 + tx] = f2bf(v);
    }
    __syncthreads();
    for (int i = 0; i < 4; i++)
      xT[(size_t)(bat*256 + c0 + ty + i*8) * 2048 + r0 + tx] = f2bf(tile[tx*33 + ty + i*8]);
  } else {                              // router: 128 blocks, 32 tokens each
    int row = t >> 3, mm = t & 7;
    int n = (bid - 9984) * 32 + row;
    const float* xr = x + (size_t)n * 256;
    float acc = 0.f;
    for (int d = 0; d < 256; d++) acc += xr[d] * Wr[d * 8 + mm];
    acc += br[mm];
    lg[row][mm] = acc;
    __syncthreads();
    if (t < 32){
      int r = t; int n2 = (bid - 9984) * 32 + r; int b = n2 >> 11;
      float mx = -1e30f;
      for (int i = 0; i < 8; i++) mx = fmaxf(mx, lg[r][i]);
      float s[8]; float sum = 0.f;
      for (int i = 0; i < 8; i++){ s[i] = __expf(lg[r][i] - mx); sum += s[i]; }
      for (int i = 0; i < 8; i++) s[i] /= sum;
      float bb[8];
      for (int i = 0; i < 8; i++) bb[i] = s[i] + bias0[b * 8 + i];
      int i1 = 0;
      for (int i = 1; i < 8; i++) if (bb[i] > bb[i1]) i1 = i;
      int i2 = -1;
      for (int i = 0; i < 8; i++){ if (i == i1) continue; if (i2 < 0 || bb[i] > bb[i2]) i2 = i; }
      float wsum = s[i1] + s[i2];
      for (int i = 0; i < 8; i++)
        rt2[r][i] = (i == i1) ? s[i1] / wsum : ((i == i2) ? s[i2] / wsum : 0.f);
    }
    __syncthreads();
    int n3 = (bid - 9984) * 32 + row;
    int b = n3 >> 11, sl = n3 & 2047;
    routT[((size_t)b * 8 + mm) * 2048 + sl] = rt2[row][mm];
  }
}

// =============== u[bm][d] += sum_{s in chunk} r*x ; rho[bm] += sum r  (atomic, skip r==0) ===============
__global__ __launch_bounds__(256) void k_usum(const unsigned short* __restrict__ xb,
                                              const float* __restrict__ routT,
                                              float* __restrict__ u, float* __restrict__ rho){
  __shared__ float rl[128];
  int bid = blockIdx.x;                 // 256 = bm(16) * sc(16)
  int sc = bid & 15, bm = bid >> 4, b = bm >> 3;
  int t = threadIdx.x;
  int s0 = sc * 128;
  if (t < 128) rl[t] = routT[(size_t)bm * 2048 + s0 + t];
  __syncthreads();
  float acc = 0.f;
  const unsigned short* xrow = xb + ((size_t)(b * 2048 + s0)) * 256 + t;
  for (int s = 0; s < 128; s++){
    float rv = rl[s];
    if (rv != 0.f)
      acc += rv * bf2f(xrow[(size_t)s * 256]);
  }
  atomicAdd(u + (size_t)bm * 256 + t, acc);
  if (t == 0){
    float rs = 0.f;
    for (int s = 0; s < 128; s++) rs += rl[s];
    atomicAdd(rho + bm, rs);
  }
}

// =============== ku/vu = WkT/WvT . u ===============
__global__ __launch_bounds__(256) void k_bias(const unsigned short* __restrict__ WkT,
                                              const unsigned short* __restrict__ WvT,
                                              const float* __restrict__ u,
                                              float* __restrict__ ku_g, float* __restrict__ vu_g){
  __shared__ float uL[256];
  int bid = blockIdx.x, t = threadIdx.x;
  int bm = bid >> 3, hseg = bid & 7, m = bm & 7;
  if (t < 64) *(f32x4*)(uL + t*4) = *(const f32x4*)(u + (size_t)bm*256 + t*4);
  __syncthreads();
  int hd = hseg * 256 + t;
  const unsigned short* wk = WkT + ((size_t)m*2048 + hd) * 256;
  const unsigned short* wv = WvT + ((size_t)m*2048 + hd) * 256;
  float sk = 0.f, sv = 0.f;
  for (int d8 = 0; d8 < 256; d8 += 8){
    bf16x8 a = *(const bf16x8*)(wk + d8);
    bf16x8 c = *(const bf16x8*)(wv + d8);
    for (int j = 0; j < 8; j++){
      sk += bf2f((unsigned short)a[j]) * uL[d8+j];
      sv += bf2f((unsigned short)c[j]) * uL[d8+j];
    }
  }
  ku_g[(size_t)bm*2048 + hd] = sk;
  vu_g[(size_t)bm*2048 + hd] = sv;
}

// =============== Gp[bm][kc] = X_chunk^T diag(r) X_chunk (256x256, K=256 tokens) ===============
__global__ __launch_bounds__(512) void k_gpart(const unsigned short* __restrict__ xT,
                                               const float* __restrict__ routT,
                                               unsigned short* __restrict__ Gp){
  __shared__ unsigned short As[256*72];     // scaled, 36 KB
  __shared__ unsigned short Bs[256*72];     // unscaled, 36 KB
  __shared__ float rl[64];
  int bid = blockIdx.x;                      // 128 = b(2) m(8) kc(8)
  int kc = bid & 7, m = (bid >> 3) & 7, b = bid >> 6;
  int bm = b * 8 + m;
  int t = threadIdx.x, lane = t & 63, w = t >> 6;
  int li = lane & 15, lgp = lane >> 4;
  int p = w >> 2, q = w & 3;
  f32x4 acc[8][4];
  for (int i = 0; i < 8; i++) for (int j = 0; j < 4; j++) acc[i][j] = (f32x4){0,0,0,0};
  for (int c4 = 0; c4 < 4; c4++){
    int s0 = kc * 256 + c4 * 64;
    if (t < 64) rl[t] = routT[(size_t)bm*2048 + s0 + t];
    __syncthreads();
    for (int qq = 0; qq < 4; qq++){
      int idx = t + qq*512;
      int row = idx >> 3, sc = (idx & 7) * 8;
      bf16x8 xv = *(const bf16x8*)(xT + ((size_t)(b*256 + row))*2048 + s0 + sc);
      *(bf16x8*)(&Bs[row*72 + sc]) = xv;
      f32x4 r0 = *(const f32x4*)(rl + sc);
      f32x4 r1 = *(const f32x4*)(rl + sc + 4);
      bf16x8 sv;
      sv[0]=(short)f2bf(bf2f((unsigned short)xv[0])*r0[0]);
      sv[1]=(short)f2bf(bf2f((unsigned short)xv[1])*r0[1]);
      sv[2]=(short)f2bf(bf2f((unsigned short)xv[2])*r0[2]);
      sv[3]=(short)f2bf(bf2f((unsigned short)xv[3])*r0[3]);
      sv[4]=(short)f2bf(bf2f((unsigned short)xv[4])*r1[0]);
      sv[5]=(short)f2bf(bf2f((unsigned short)xv[5])*r1[1]);
      sv[6]=(short)f2bf(bf2f((unsigned short)xv[6])*r1[2]);
      sv[7]=(short)f2bf(bf2f((unsigned short)xv[7])*r1[3]);
      *(bf16x8*)(&As[row*72 + sc]) = sv;
    }
    __syncthreads();
    for (int kk = 0; kk < 2; kk++){
      bf16x8 Bf[4];
      for (int j = 0; j < 4; j++)
        Bf[j] = *(const bf16x8*)(&Bs[(q*64 + j*16 + li)*72 + kk*32 + lgp*8]);
      for (int i = 0; i < 8; i++){
        bf16x8 Af = *(const bf16x8*)(&As[(p*128 + i*16 + li)*72 + kk*32 + lgp*8]);
        for (int j = 0; j < 4; j++)
          acc[i][j] = __builtin_amdgcn_mfma_f32_16x16x32_bf16(Af, Bf[j], acc[i][j], 0, 0, 0);
      }
    }
    __syncthreads();
  }
  // bounce C (row=d1 from A, col=d2 from B) -> Gp[bm][kc][d2][d1]
  unsigned short* Cs = As;                   // 64 x 264 overlay
  for (int ph = 0; ph < 4; ph++){
    if (q == ph){
      for (int i = 0; i < 8; i++)
        for (int j = 0; j < 4; j++){
          int rr = j*16 + li, cc = p*128 + i*16 + lgp*4;
          *(unsigned long long*)(&Cs[rr*264 + cc]) =
            pk4(acc[i][j][0], acc[i][j][1], acc[i][j][2], acc[i][j][3]);
        }
    }
    __syncthreads();
    for (int qq = 0; qq < 4; qq++){
      int idx = t + qq*512;
      int row = idx >> 5, cc = (idx & 31) * 8;
      *(bf16x8*)(Gp + (((size_t)bm*8 + kc) << 16) + (size_t)(ph*64 + row)*256 + cc) =
        *(const bf16x8*)(&Cs[row*264 + cc]);
    }
    __syncthreads();
  }
}

// =============== reduce Gp over kc -> G[bm][256][256] ===============
__global__ __launch_bounds__(256) void k_gred(const unsigned short* __restrict__ Gp,
                                              unsigned short* __restrict__ G){
  int idx = blockIdx.x * 256 + threadIdx.x;
  int bm = idx >> 13; size_t e8 = (size_t)(idx & 8191) * 8;
  float s[8] = {0,0,0,0,0,0,0,0};
  for (int kc = 0; kc < 8; kc++){
    bf16x8 v = *(const bf16x8*)(Gp + (((size_t)bm*8 + kc) << 16) + e8);
    for (int j = 0; j < 8; j++) s[j] += bf2f((unsigned short)v[j]);
  }
  *(unsigned long long*)(G + ((size_t)bm << 16) + e8)     = pk4(s[0], s[1], s[2], s[3]);
  *(unsigned long long*)(G + ((size_t)bm << 16) + e8 + 4) = pk4(s[4], s[5], s[6], s[7]);
}

// =============== per (b,m,h,vh): T = G@Wv (LDS), mem_part = Wk^T@T + rank-1 ===============
__global__ __launch_bounds__(512) void k_memh(const unsigned short* __restrict__ G,
                                              const unsigned short* __restrict__ WkT,
                                              const unsigned short* __restrict__ WvT,
                                              const float* __restrict__ bk,
                                              const float* __restrict__ bv,
                                              const float* __restrict__ ku_g,
                                              const float* __restrict__ vu_g,
                                              const float* __restrict__ rho,
                                              unsigned short* __restrict__ mempart){
  __shared__ unsigned short TT[128*256];     // 64 KB, XOR-swizzled [vd][d1]
  int bid = blockIdx.x;                       // 256 = b(2) m(8) h(8) vq(2)
  int vq = bid & 1, h = (bid >> 1) & 7, m = (bid >> 4) & 7, b = bid >> 7;
  int bm = b * 8 + m, bh = b * 8 + h;
  int hd0 = h * 256, vd0 = vq * 128;
  int t = threadIdx.x, lane = t & 63, w = t >> 6;
  int li = lane & 15, lgp = lane >> 4;
  int r = w >> 2, c = w & 3;
  // stage 1: T[d1 256][vd 128] = G @ Wv_slice
  f32x4 a1[8][2];
  for (int i = 0; i < 8; i++) for (int j = 0; j < 2; j++) a1[i][j] = (f32x4){0,0,0,0};
  for (int kk = 0; kk < 8; kk++){
    bf16x8 Bf[2];
    for (int j = 0; j < 2; j++)
      Bf[j] = *(const bf16x8*)(WvT + ((size_t)m*2048 + hd0 + vd0 + c*32 + j*16 + li)*256 + kk*32 + lgp*8);
    for (int i = 0; i < 8; i++){
      bf16x8 Af = *(const bf16x8*)(G + ((size_t)bm << 16) + (size_t)(r*128 + i*16 + li)*256 + kk*32 + lgp*8);
      for (int j = 0; j < 2; j++)
        a1[i][j] = __builtin_amdgcn_mfma_f32_16x16x32_bf16(Af, Bf[j], a1[i][j], 0, 0, 0);
    }
  }
  for (int i = 0; i < 8; i++)
    for (int j = 0; j < 2; j++){
      int vdl = c*32 + j*16 + li;
      int d1 = r*128 + i*16 + lgp*4;
      int bo2 = (vdl*512 + d1*2) ^ ((vdl & 7) << 4);
      *(unsigned long long*)((char*)TT + bo2) = pk4(a1[i][j][0], a1[i][j][1], a1[i][j][2], a1[i][j][3]);
    }
  __syncthreads();
  // stage 2: mem[kd 256][vd 128] = Wk^T @ T
  f32x4 a2[8][2];
  for (int i = 0; i < 8; i++) for (int j = 0; j < 2; j++) a2[i][j] = (f32x4){0,0,0,0};
  for (int kk = 0; kk < 8; kk++){
    bf16x8 Bf[2];
    for (int j = 0; j < 2; j++){
      int vdl = c*32 + j*16 + li;
      int bo2 = (vdl*512 + (kk*32 + lgp*8)*2) ^ ((vdl & 7) << 4);
      Bf[j] = *(const bf16x8*)((char*)TT + bo2);
    }
    for (int i = 0; i < 8; i++){
      bf16x8 Af = *(const bf16x8*)(WkT + ((size_t)m*2048 + hd0 + r*128 + i*16 + li)*256 + kk*32 + lgp*8);
      for (int j = 0; j < 2; j++)
        a2[i][j] = __builtin_amdgcn_mfma_f32_16x16x32_bf16(Af, Bf[j], a2[i][j], 0, 0, 0);
    }
  }
  __syncthreads();
  // epilogue (rank-1 bias terms) + coalescing bounce
  float rhov = rho[bm];
  unsigned short* Cs = TT;                    // 32 x 264 overlay
  for (int ph = 0; ph < 4; ph++){
    if (c == ph){
      for (int j = 0; j < 2; j++){
        int vdl = c*32 + j*16 + li;
        int vdg = hd0 + vd0 + vdl;
        float bvv = bv[(size_t)m*2048 + vdg];
        float vuv = vu_g[(size_t)bm*2048 + vdg];
        float bb = vuv + rhov * bvv;
        for (int i = 0; i < 8; i++){
          int kd = r*128 + i*16 + lgp*4;
          f32x4 ku4 = *(const f32x4*)(ku_g + (size_t)bm*2048 + hd0 + kd);
          f32x4 bk4 = *(const f32x4*)(bk + (size_t)m*2048 + hd0 + kd);
          float v0 = a2[i][j][0] + ku4[0]*bvv + bk4[0]*bb;
          float v1 = a2[i][j][1] + ku4[1]*bvv + bk4[1]*bb;
          float v2 = a2[i][j][2] + ku4[2]*bvv + bk4[2]*bb;
          float v3 = a2[i][j][3] + ku4[3]*bvv + bk4[3]*bb;
          *(unsigned long long*)(&Cs[(j*16 + li)*264 + kd]) = pk4(v0, v1, v2, v3);
        }
      }
    }
    __syncthreads();
    for (int qq = 0; qq < 2; qq++){
      int idx = t + qq*512;
      int row = idx >> 5, cc = (idx & 31) * 8;
      *(bf16x8*)(mempart + ((size_t)((bh*2 + vq)*8 + m))*32768 + (size_t)(ph*32 + row)*256 + cc) =
        *(const bf16x8*)(&Cs[row*264 + cc]);
    }
    __syncthreads();
  }
}

// =============== reduce mempart over m -> memT[bh][vd][kd] ===============
__global__ __launch_bounds__(256) void k_mred(const unsigned short* __restrict__ mempart,
                                              unsigned short* __restrict__ memT){
  int idx = blockIdx.x * 256 + threadIdx.x;   // 131072
  int bh = idx >> 13; int rem = idx & 8191;
  int vd = rem >> 5, kd0 = (rem & 31) * 8;
  int vq = vd >> 7, vdl = vd & 127;
  size_t src = ((size_t)((bh*2 + vq)*8))*32768 + (size_t)vdl*256 + kd0;
  float s[8] = {0,0,0,0,0,0,0,0};
  for (int m = 0; m < 8; m++){
    bf16x8 v = *(const bf16x8*)(mempart + src + (size_t)m*32768);
    for (int j = 0; j < 8; j++) s[j] += bf2f((unsigned short)v[j]);
  }
  size_t dst = (size_t)bh*65536 + (size_t)vd*256 + kd0;
  *(unsigned long long*)(memT + dst)     = pk4(s[0], s[1], s[2], s[3]);
  *(unsigned long long*)(memT + dst + 4) = pk4(s[4], s[5], s[6], s[7]);
}

// =============== E_h = Wq_h @ mem_h  -> Eb[b][d][h*256+vd]; qbAll = bq_h . mem_h ===============
__global__ __launch_bounds__(512) void k_emat(const unsigned short* __restrict__ memT,
                                              const unsigned short* __restrict__ Wqb,
                                              const float* __restrict__ bq,
                                              unsigned short* __restrict__ Eb,
                                              float* __restrict__ qbAll){
  __shared__ unsigned short Cs[32*264];
  int bid = blockIdx.x;                        // 32 = bh(16) * dseg(2)
  int dseg = bid & 1, bh = bid >> 1;
  int b = bh >> 3, h = bh & 7;
  int hd0 = h * 256, d0 = dseg * 128;
  int t = threadIdx.x, lane = t & 63, w = t >> 6;
  int li = lane & 15, lgp = lane >> 4;
  int r = w >> 2, c = w & 3;
  // out [vd 256][d 128]: A = memT rows vd, B = Wqb rows d (K = kd 256)
  f32x4 acc[8][2];
  for (int i = 0; i < 8; i++) for (int j = 0; j < 2; j++) acc[i][j] = (f32x4){0,0,0,0};
  for (int kk = 0; kk < 8; kk++){
    bf16x8 Bf[2];
    for (int j = 0; j < 2; j++)
      Bf[j] = *(const bf16x8*)(Wqb + (size_t)(d0 + c*32 + j*16 + li)*2048 + hd0 + kk*32 + lgp*8);
    for (int i = 0; i < 8; i++){
      bf16x8 Af = *(const bf16x8*)(memT + (size_t)bh*65536 + (size_t)(r*128 + i*16 + li)*256 + kk*32 + lgp*8);
      for (int j = 0; j < 2; j++)
        acc[i][j] = __builtin_amdgcn_mfma_f32_16x16x32_bf16(Af, Bf[j], acc[i][j], 0, 0, 0);
    }
  }
  // qb: qbAll[b][hd0+vd] = sum_kd bq[hd0+kd]*mem[kd][vd]
  if (dseg == 0 && t < 256){
    const unsigned short* mrow = memT + (size_t)bh*65536 + (size_t)t*256;
    float s = 0.f;
    for (int k8 = 0; k8 < 256; k8 += 8){
      bf16x8 v = *(const bf16x8*)(mrow + k8);
      for (int e = 0; e < 8; e++) s += bf2f((unsigned short)v[e]) * bq[hd0 + k8 + e];
    }
    qbAll[(size_t)b*2048 + hd0 + t] = s;
  }
  // bounce: C row=vd, col=d -> Eb[b][d][hd0+vd]
  for (int ph = 0; ph < 4; ph++){
    if (c == ph){
      for (int i = 0; i < 8; i++)
        for (int j = 0; j < 2; j++){
          int dl = j*16 + li;
          int vd4 = r*128 + i*16 + lgp*4;
          *(unsigned long long*)(&Cs[dl*264 + vd4]) =
            pk4(acc[i][j][0], acc[i][j][1], acc[i][j][2], acc[i][j][3]);
        }
    }
    __syncthreads();
    for (int qq = 0; qq < 2; qq++){
      int idx = t + qq*512;
      int row = idx >> 5, cc = (idx & 31) * 8;
      *(bf16x8*)(Eb + (size_t)b*524288 + (size_t)(d0 + ph*32 + row)*2048 + hd0 + cc) =
        *(const bf16x8*)(&Cs[row*264 + cc]);
    }
    __syncthreads();
  }
}

// =============== F[b][do][d] = Eb[b] x Wo (full K=2048, no atomics); tail blocks: c0 ===============
__global__ __launch_bounds__(512) void k_fmat(const unsigned short* __restrict__ Eb,
                                              const unsigned short* __restrict__ WoT,
                                              const float* __restrict__ qbAll,
                                              const float* __restrict__ bo,
                                              float* __restrict__ Facc,
                                              float* __restrict__ c0acc){
  int bid = blockIdx.x;
  int t = threadIdx.x;
  if (bid >= 32){                              // c0 blocks: bid 32,33 -> b
    int b = bid - 32;
    if (t < 256){
      float s = bo[t];
      const unsigned short* wrow = WoT + (size_t)t * 2048;
      const float* qrow = qbAll + (size_t)b * 2048;
      for (int k8 = 0; k8 < 2048; k8 += 8){
        bf16x8 v = *(const bf16x8*)(wrow + k8);
        for (int e = 0; e < 8; e++) s += bf2f((unsigned short)v[e]) * qrow[k8 + e];
      }
      c0acc[(size_t)b * 256 + t] = s;
    }
    return;
  }
  // F blocks: bid = b*16 + doseg*4 + dseg ; 64x64 tile, K = 2048
  int dseg = bid & 3, doseg = (bid >> 2) & 3, b = bid >> 4;
  int do0 = doseg * 64, d0 = dseg * 64;
  int lane = t & 63, w = t >> 6;
  int li = lane & 15, lgp = lane >> 4;
  int r = w >> 2, c = w & 3;                   // r: do 2x32, c: d 4x16
  f32x4 acc[2];
  acc[0] = (f32x4){0,0,0,0}; acc[1] = (f32x4){0,0,0,0};
  const unsigned short* bp = Eb + (size_t)b*524288 + (size_t)(d0 + c*16 + li)*2048 + lgp*8;
  const unsigned short* ap = WoT + (size_t)(do0 + r*32 + li)*2048 + lgp*8;
  for (int kk = 0; kk < 64; kk++){
    bf16x8 Bf = *(const bf16x8*)(bp + kk*32);
    bf16x8 Af0 = *(const bf16x8*)(ap + kk*32);
    bf16x8 Af1 = *(const bf16x8*)(ap + kk*32 + 16*2048);
    acc[0] = __builtin_amdgcn_mfma_f32_16x16x32_bf16(Af0, Bf, acc[0], 0, 0, 0);
    acc[1] = __builtin_amdgcn_mfma_f32_16x16x32_bf16(Af1, Bf, acc[1], 0, 0, 0);
  }
  int dd = d0 + c*16 + li;
  for (int i = 0; i < 2; i++){
    int dor = do0 + r*32 + i*16 + lgp*4;
    float* p = Facc + (size_t)b*65536 + (size_t)dor*256 + dd;
    p[0]   = acc[i][0];
    p[256] = acc[i][1];
    p[512] = acc[i][2];
    p[768] = acc[i][3];
  }
}

// =============== out[tok][do] = x @ F + c0 (f32 direct) ===============
__global__ __launch_bounds__(512) void k_final2(const float* __restrict__ Facc,
                                                const unsigned short* __restrict__ xb,
                                                const float* __restrict__ c0acc,
                                                float* __restrict__ out){
  int bid = blockIdx.x;                        // 64 = b(2) * tc(32), 64 tokens each
  int tc = bid & 31, b = bid >> 5;
  int t = threadIdx.x, lane = t & 63, w = t >> 6;
  int li = lane & 15, lgp = lane >> 4;
  int r = w >> 1, c = w & 1;                   // r: do 4x64, c: tok 2x32
  int tok0 = b * 2048 + tc * 64;
  f32x4 acc[4][2];
  for (int i = 0; i < 4; i++) for (int j = 0; j < 2; j++) acc[i][j] = (f32x4){0,0,0,0};
  for (int kk = 0; kk < 8; kk++){
    bf16x8 Bf[2];
    for (int j = 0; j < 2; j++)
      Bf[j] = *(const bf16x8*)(xb + (size_t)(tok0 + c*32 + j*16 + li)*256 + kk*32 + lgp*8);
    for (int i = 0; i < 4; i++){
      const float* Fp = Facc + (size_t)b*65536 + (size_t)(r*64 + i*16 + li)*256 + kk*32 + lgp*8;
      f32x4 fa = *(const f32x4*)(Fp);
      f32x4 fb = *(const f32x4*)(Fp + 4);
      union { unsigned long long q[2]; bf16x8 v; } af;
      af.q[0] = pk4(fa[0], fa[1], fa[2], fa[3]);
      af.q[1] = pk4(fb[0], fb[1], fb[2], fb[3]);
      for (int j = 0; j < 2; j++)
        acc[i][j] = __builtin_amdgcn_mfma_f32_16x16x32_bf16(af.v, Bf[j], acc[i][j], 0, 0, 0);
    }
  }
  // C row=do, col=tok: direct f32x4 stores (sector-complete per wave)
  for (int i = 0; i < 4; i++){
    int dol = r*64 + i*16 + lgp*4;
    f32x4 c4 = *(const f32x4*)(c0acc + (size_t)b*256 + dol);
    for (int j = 0; j < 2; j++){
      int tokl = c*32 + j*16 + li;
      f32x4 v = acc[i][j];
      v[0] += c4[0]; v[1] += c4[1]; v[2] += c4[2]; v[3] += c4[3];
      *(f32x4*)(out + (size_t)(tok0 + tokl)*256 + dol) = v;
    }
  }
}

extern "C" void kernel_launch(void* const* d_in, const int* in_sizes, int n_in,
                              void* d_out, int out_size, void* d_ws, size_t ws_size,
                              hipStream_t stream) {
  const float* x     = (const float*)d_in[0];
  const float* Wq    = (const float*)d_in[1];
  const float* bq    = (const float*)d_in[2];
  const float* Wr    = (const float*)d_in[3];
  const float* br    = (const float*)d_in[4];
  const float* Wk    = (const float*)d_in[5];
  const float* bk    = (const float*)d_in[6];
  const float* Wv    = (const float*)d_in[7];
  const float* bv    = (const float*)d_in[8];
  const float* Wo    = (const float*)d_in[9];
  const float* bo    = (const float*)d_in[10];
  const float* bias0 = (const float*)d_in[11];
  float* out = (float*)d_out;

  char* ws = (char*)d_ws;
  size_t off = 0;
  auto alloc = [&](size_t bytes) -> char* {
    char* p = ws + off;
    off = (off + bytes + 255) & ~(size_t)255;
    return p;
  };
  unsigned short* xb   = (unsigned short*)alloc((size_t)4096 * 256 * 2);      // 2 MB
  unsigned short* xT   = (unsigned short*)alloc((size_t)2 * 256 * 2048 * 2);  // 2 MB
  unsigned short* Wqb  = (unsigned short*)alloc((size_t)256 * 2048 * 2);      // 1 MB
  unsigned short* WkT  = (unsigned short*)alloc((size_t)8 * 2048 * 256 * 2);  // 8 MB
  unsigned short* WvT  = (unsigned short*)alloc((size_t)8 * 2048 * 256 * 2);  // 8 MB
  unsigned short* WoT  = (unsigned short*)alloc((size_t)256 * 2048 * 2);      // 1 MB
  float*          routT= (float*)alloc((size_t)16 * 2048 * 4);                // 128 KB
  float*          u    = (float*)alloc((size_t)16 * 256 * 4);                 // 16 KB
  float*          rho  = (float*)alloc((size_t)16 * 4);
  float*          ku_g = (float*)alloc((size_t)16 * 2048 * 4);
  float*          vu_g = (float*)alloc((size_t)16 * 2048 * 4);
  unsigned short* Gp   = (unsigned short*)alloc((size_t)16 * 8 * 65536 * 2);  // 16 MB
  unsigned short* G    = (unsigned short*)alloc((size_t)16 * 65536 * 2);      // 2 MB
  unsigned short* memT = (unsigned short*)alloc((size_t)16 * 65536 * 2);      // 2 MB
  unsigned short* Eb   = (unsigned short*)alloc((size_t)2 * 256 * 2048 * 2);  // 2 MB
  float*          qbAll= (float*)alloc((size_t)2 * 2048 * 4);
  float*          Facc = (float*)alloc((size_t)(2 * 65536 + 2 * 256) * 4);    // F + c0 contiguous
  float*          c0acc= Facc + 2 * 65536;
  unsigned short* mempart = Gp;   // Gp dead after k_gred
  (void)ws_size; (void)in_sizes; (void)n_in; (void)out_size;

  hipMemsetAsync(u, 0, (size_t)16 * 256 * 4 + 256, stream);   // u + rho (contiguous allocs)
  k_prep<<<10112, 256, 0, stream>>>(x, Wq, Wr, br, Wk, Wv, Wo, bias0,
                                    WkT, WvT, WoT, Wqb, xb, xT, routT);
  k_usum<<<256, 256, 0, stream>>>(xb, routT, u, rho);
  k_bias<<<128, 256, 0, stream>>>(WkT, WvT, u, ku_g, vu_g);
  k_gpart<<<128, 512, 0, stream>>>(xT, routT, Gp);
  k_gred<<<512, 256, 0, stream>>>(Gp, G);
  k_memh<<<256, 512, 0, stream>>>(G, WkT, WvT, bk, bv, ku_g, vu_g, rho, mempart);
  k_mred<<<512, 256, 0, stream>>>(mempart, memT);
  k_emat<<<32, 512, 0, stream>>>(memT, Wqb, bq, Eb, qbAll);
  k_fmat<<<34, 512, 0, stream>>>(Eb, WoT, qbAll, bo, Facc, c0acc);
  k_final2<<<64, 512, 0, stream>>>(Facc, xb, c0acc, out);
}

// Round 6
// 224.419 us; speedup vs baseline: 1.3504x; 1.0464x over previous
//
#include <hip/hip_runtime.h>

typedef __attribute__((ext_vector_type(8))) short bf16x8;
typedef __attribute__((ext_vector_type(4))) float f32x4;

#define DEV static __device__ __forceinline__

DEV unsigned short f2bf(float f){
  union { float f; unsigned u; } v; v.f = f;
  unsigned r = v.u + 0x7fffu + ((v.u >> 16) & 1u);
  return (unsigned short)(r >> 16);
}
DEV float bf2f(unsigned short u){
  union { unsigned u; float f; } v; v.u = ((unsigned)u) << 16;
  return v.f;
}
DEV unsigned long long pk4(float a, float b, float c, float d){
  unsigned lo = (unsigned)f2bf(a) | ((unsigned)f2bf(b) << 16);
  unsigned hi = (unsigned)f2bf(c) | ((unsigned)f2bf(d) << 16);
  return ((unsigned long long)hi << 32) | lo;
}

// =============== fused prep: weight transposes/converts + x prep + router ===============
__global__ __launch_bounds__(256) void k_prep(const float* __restrict__ x,
                                              const float* __restrict__ Wq,
                                              const float* __restrict__ Wr,
                                              const float* __restrict__ br,
                                              const float* __restrict__ Wk,
                                              const float* __restrict__ Wv,
                                              const float* __restrict__ Wo,
                                              const float* __restrict__ bias0,
                                              unsigned short* __restrict__ WkT,
                                              unsigned short* __restrict__ WvT,
                                              unsigned short* __restrict__ WoT,
                                              unsigned short* __restrict__ Wqb,
                                              unsigned short* __restrict__ xb,
                                              unsigned short* __restrict__ xT,
                                              float* __restrict__ routT){
  __shared__ float tile[32*33];
  __shared__ float lg[32][8];
  __shared__ float rt2[32][8];
  int bid = blockIdx.x;
  int t = threadIdx.x;
  int tx = t & 31, ty = t >> 5;

  if (bid < 8192){                      // Wk (0..4095) / Wv (4096..8191): [8][256][2048] -> [8][2048][256]
    const float* src = (bid < 4096) ? Wk : Wv;
    unsigned short* dst = (bid < 4096) ? WkT : WvT;
    int q = bid & 4095;
    int bat = q >> 9, rem = q & 511;
    int c0 = (rem >> 3) * 32, r0 = (rem & 7) * 32;
    size_t boff = (size_t)bat * 256 * 2048;
    for (int i = 0; i < 4; i++)
      tile[(ty + i*8)*33 + tx] = src[boff + (size_t)(r0 + ty + i*8) * 2048 + c0 + tx];
    __syncthreads();
    for (int i = 0; i < 4; i++)
      dst[boff + (size_t)(c0 + ty + i*8) * 256 + r0 + tx] = f2bf(tile[tx*33 + ty + i*8]);
  } else if (bid < 8704){               // Wo: [2048][256] -> [256][2048]
    int q = bid - 8192;
    int c0 = (q >> 6) * 32, r0 = (q & 63) * 32;
    for (int i = 0; i < 4; i++)
      tile[(ty + i*8)*33 + tx] = Wo[(size_t)(r0 + ty + i*8) * 256 + c0 + tx];
    __syncthreads();
    for (int i = 0; i < 4; i++)
      WoT[(size_t)(c0 + ty + i*8) * 2048 + r0 + tx] = f2bf(tile[tx*33 + ty + i*8]);
  } else if (bid < 8960){               // Wq plain convert [256][2048]
    int q = bid - 8704;
    size_t idx = (size_t)q * 2048 + t * 8;
    f32x4 a = *(const f32x4*)(Wq + idx);
    f32x4 b = *(const f32x4*)(Wq + idx + 4);
    *(unsigned long long*)(Wqb + idx)     = pk4(a[0], a[1], a[2], a[3]);
    *(unsigned long long*)(Wqb + idx + 4) = pk4(b[0], b[1], b[2], b[3]);
  } else if (bid < 9984){               // x: [2][2048][256] -> xb [4096][256] + xT [2][256][2048]
    int q = bid - 8960;
    int bat = q >> 9, rem = q & 511;
    int c0 = (rem >> 6) * 32, r0 = (rem & 63) * 32;
    size_t boff = (size_t)bat * 2048 * 256;
    for (int i = 0; i < 4; i++){
      float v = x[boff + (size_t)(r0 + ty + i*8) * 256 + c0 + tx];
      tile[(ty + i*8)*33 + tx] = v;
      xb[boff + (size_t)(r0 + ty + i*8) * 256 + c0 + tx] = f2bf(v);
    }
    __syncthreads();
    for (int i = 0; i < 4; i++)
      xT[(size_t)(bat*256 + c0 + ty + i*8) * 2048 + r0 + tx] = f2bf(tile[tx*33 + ty + i*8]);
  } else {                              // router: 128 blocks, 32 tokens each
    int row = t >> 3, mm = t & 7;
    int n = (bid - 9984) * 32 + row;
    const float* xr = x + (size_t)n * 256;
    float acc = 0.f;
    for (int d = 0; d < 256; d++) acc += xr[d] * Wr[d * 8 + mm];
    acc += br[mm];
    lg[row][mm] = acc;
    __syncthreads();
    if (t < 32){
      int r = t; int n2 = (bid - 9984) * 32 + r; int b = n2 >> 11;
      float mx = -1e30f;
      for (int i = 0; i < 8; i++) mx = fmaxf(mx, lg[r][i]);
      float s[8]; float sum = 0.f;
      for (int i = 0; i < 8; i++){ s[i] = __expf(lg[r][i] - mx); sum += s[i]; }
      for (int i = 0; i < 8; i++) s[i] /= sum;
      float bb[8];
      for (int i = 0; i < 8; i++) bb[i] = s[i] + bias0[b * 8 + i];
      int i1 = 0;
      for (int i = 1; i < 8; i++) if (bb[i] > bb[i1]) i1 = i;
      int i2 = -1;
      for (int i = 0; i < 8; i++){ if (i == i1) continue; if (i2 < 0 || bb[i] > bb[i2]) i2 = i; }
      float wsum = s[i1] + s[i2];
      for (int i = 0; i < 8; i++)
        rt2[r][i] = (i == i1) ? s[i1] / wsum : ((i == i2) ? s[i2] / wsum : 0.f);
    }
    __syncthreads();
    int n3 = (bid - 9984) * 32 + row;
    int b = n3 >> 11, sl = n3 & 2047;
    routT[((size_t)b * 8 + mm) * 2048 + sl] = rt2[row][mm];
  }
}

// =============== u[bm][d] += sum_{s in chunk} r*x ; rho[bm] += sum r  (atomic, skip r==0) ===============
__global__ __launch_bounds__(256) void k_usum(const unsigned short* __restrict__ xb,
                                              const float* __restrict__ routT,
                                              float* __restrict__ u, float* __restrict__ rho){
  __shared__ float rl[128];
  int bid = blockIdx.x;                 // 256 = bm(16) * sc(16)
  int sc = bid & 15, bm = bid >> 4, b = bm >> 3;
  int t = threadIdx.x;
  int s0 = sc * 128;
  if (t < 128) rl[t] = routT[(size_t)bm * 2048 + s0 + t];
  __syncthreads();
  float acc = 0.f;
  const unsigned short* xrow = xb + ((size_t)(b * 2048 + s0)) * 256 + t;
  for (int s = 0; s < 128; s++){
    float rv = rl[s];
    if (rv != 0.f)
      acc += rv * bf2f(xrow[(size_t)s * 256]);
  }
  atomicAdd(u + (size_t)bm * 256 + t, acc);
  if (t == 0){
    float rs = 0.f;
    for (int s = 0; s < 128; s++) rs += rl[s];
    atomicAdd(rho + bm, rs);
  }
}

// =============== ku/vu = WkT/WvT . u ===============
__global__ __launch_bounds__(256) void k_bias(const unsigned short* __restrict__ WkT,
                                              const unsigned short* __restrict__ WvT,
                                              const float* __restrict__ u,
                                              float* __restrict__ ku_g, float* __restrict__ vu_g){
  __shared__ float uL[256];
  int bid = blockIdx.x, t = threadIdx.x;
  int bm = bid >> 3, hseg = bid & 7, m = bm & 7;
  if (t < 64) *(f32x4*)(uL + t*4) = *(const f32x4*)(u + (size_t)bm*256 + t*4);
  __syncthreads();
  int hd = hseg * 256 + t;
  const unsigned short* wk = WkT + ((size_t)m*2048 + hd) * 256;
  const unsigned short* wv = WvT + ((size_t)m*2048 + hd) * 256;
  float sk = 0.f, sv = 0.f;
  for (int d8 = 0; d8 < 256; d8 += 8){
    bf16x8 a = *(const bf16x8*)(wk + d8);
    bf16x8 c = *(const bf16x8*)(wv + d8);
    for (int j = 0; j < 8; j++){
      sk += bf2f((unsigned short)a[j]) * uL[d8+j];
      sv += bf2f((unsigned short)c[j]) * uL[d8+j];
    }
  }
  ku_g[(size_t)bm*2048 + hd] = sk;
  vu_g[(size_t)bm*2048 + hd] = sv;
}

// =============== Gp[bm][kc] = X_chunk^T diag(r) X_chunk (256x256, K=256 tokens) ===============
__global__ __launch_bounds__(512) void k_gpart(const unsigned short* __restrict__ xT,
                                               const float* __restrict__ routT,
                                               unsigned short* __restrict__ Gp){
  __shared__ unsigned short As[256*72];     // scaled, 36 KB
  __shared__ unsigned short Bs[256*72];     // unscaled, 36 KB
  __shared__ float rl[64];
  int bid = blockIdx.x;                      // 128 = b(2) m(8) kc(8)
  int kc = bid & 7, m = (bid >> 3) & 7, b = bid >> 6;
  int bm = b * 8 + m;
  int t = threadIdx.x, lane = t & 63, w = t >> 6;
  int li = lane & 15, lgp = lane >> 4;
  int p = w >> 2, q = w & 3;
  f32x4 acc[8][4];
  for (int i = 0; i < 8; i++) for (int j = 0; j < 4; j++) acc[i][j] = (f32x4){0,0,0,0};
  for (int c4 = 0; c4 < 4; c4++){
    int s0 = kc * 256 + c4 * 64;
    if (t < 64) rl[t] = routT[(size_t)bm*2048 + s0 + t];
    __syncthreads();
    for (int qq = 0; qq < 4; qq++){
      int idx = t + qq*512;
      int row = idx >> 3, sc = (idx & 7) * 8;
      bf16x8 xv = *(const bf16x8*)(xT + ((size_t)(b*256 + row))*2048 + s0 + sc);
      *(bf16x8*)(&Bs[row*72 + sc]) = xv;
      f32x4 r0 = *(const f32x4*)(rl + sc);
      f32x4 r1 = *(const f32x4*)(rl + sc + 4);
      bf16x8 sv;
      sv[0]=(short)f2bf(bf2f((unsigned short)xv[0])*r0[0]);
      sv[1]=(short)f2bf(bf2f((unsigned short)xv[1])*r0[1]);
      sv[2]=(short)f2bf(bf2f((unsigned short)xv[2])*r0[2]);
      sv[3]=(short)f2bf(bf2f((unsigned short)xv[3])*r0[3]);
      sv[4]=(short)f2bf(bf2f((unsigned short)xv[4])*r1[0]);
      sv[5]=(short)f2bf(bf2f((unsigned short)xv[5])*r1[1]);
      sv[6]=(short)f2bf(bf2f((unsigned short)xv[6])*r1[2]);
      sv[7]=(short)f2bf(bf2f((unsigned short)xv[7])*r1[3]);
      *(bf16x8*)(&As[row*72 + sc]) = sv;
    }
    __syncthreads();
    for (int kk = 0; kk < 2; kk++){
      bf16x8 Bf[4];
      for (int j = 0; j < 4; j++)
        Bf[j] = *(const bf16x8*)(&Bs[(q*64 + j*16 + li)*72 + kk*32 + lgp*8]);
      for (int i = 0; i < 8; i++){
        bf16x8 Af = *(const bf16x8*)(&As[(p*128 + i*16 + li)*72 + kk*32 + lgp*8]);
        for (int j = 0; j < 4; j++)
          acc[i][j] = __builtin_amdgcn_mfma_f32_16x16x32_bf16(Af, Bf[j], acc[i][j], 0, 0, 0);
      }
    }
    __syncthreads();
  }
  // bounce C (row=d1 from A, col=d2 from B) -> Gp[bm][kc][d2][d1]
  unsigned short* Cs = As;                   // 64 x 264 overlay
  for (int ph = 0; ph < 4; ph++){
    if (q == ph){
      for (int i = 0; i < 8; i++)
        for (int j = 0; j < 4; j++){
          int rr = j*16 + li, cc = p*128 + i*16 + lgp*4;
          *(unsigned long long*)(&Cs[rr*264 + cc]) =
            pk4(acc[i][j][0], acc[i][j][1], acc[i][j][2], acc[i][j][3]);
        }
    }
    __syncthreads();
    for (int qq = 0; qq < 4; qq++){
      int idx = t + qq*512;
      int row = idx >> 5, cc = (idx & 31) * 8;
      *(bf16x8*)(Gp + (((size_t)bm*8 + kc) << 16) + (size_t)(ph*64 + row)*256 + cc) =
        *(const bf16x8*)(&Cs[row*264 + cc]);
    }
    __syncthreads();
  }
}

// =============== reduce Gp over kc -> G[bm][256][256] ===============
__global__ __launch_bounds__(256) void k_gred(const unsigned short* __restrict__ Gp,
                                              unsigned short* __restrict__ G){
  int idx = blockIdx.x * 256 + threadIdx.x;
  int bm = idx >> 13; size_t e8 = (size_t)(idx & 8191) * 8;
  float s[8] = {0,0,0,0,0,0,0,0};
  for (int kc = 0; kc < 8; kc++){
    bf16x8 v = *(const bf16x8*)(Gp + (((size_t)bm*8 + kc) << 16) + e8);
    for (int j = 0; j < 8; j++) s[j] += bf2f((unsigned short)v[j]);
  }
  *(unsigned long long*)(G + ((size_t)bm << 16) + e8)     = pk4(s[0], s[1], s[2], s[3]);
  *(unsigned long long*)(G + ((size_t)bm << 16) + e8 + 4) = pk4(s[4], s[5], s[6], s[7]);
}

// =============== per (b,m,h,vh): T = G@Wv (LDS), mem_part = Wk^T@T + rank-1 ===============
__global__ __launch_bounds__(512) void k_memh(const unsigned short* __restrict__ G,
                                              const unsigned short* __restrict__ WkT,
                                              const unsigned short* __restrict__ WvT,
                                              const float* __restrict__ bk,
                                              const float* __restrict__ bv,
                                              const float* __restrict__ ku_g,
                                              const float* __restrict__ vu_g,
                                              const float* __restrict__ rho,
                                              unsigned short* __restrict__ mempart){
  __shared__ unsigned short TT[128*256];     // 64 KB, XOR-swizzled [vd][d1]
  int bid = blockIdx.x;                       // 256 = b(2) m(8) h(8) vq(2)
  int vq = bid & 1, h = (bid >> 1) & 7, m = (bid >> 4) & 7, b = bid >> 7;
  int bm = b * 8 + m, bh = b * 8 + h;
  int hd0 = h * 256, vd0 = vq * 128;
  int t = threadIdx.x, lane = t & 63, w = t >> 6;
  int li = lane & 15, lgp = lane >> 4;
  int r = w >> 2, c = w & 3;
  // stage 1: T[d1 256][vd 128] = G @ Wv_slice
  f32x4 a1[8][2];
  for (int i = 0; i < 8; i++) for (int j = 0; j < 2; j++) a1[i][j] = (f32x4){0,0,0,0};
  for (int kk = 0; kk < 8; kk++){
    bf16x8 Bf[2];
    for (int j = 0; j < 2; j++)
      Bf[j] = *(const bf16x8*)(WvT + ((size_t)m*2048 + hd0 + vd0 + c*32 + j*16 + li)*256 + kk*32 + lgp*8);
    for (int i = 0; i < 8; i++){
      bf16x8 Af = *(const bf16x8*)(G + ((size_t)bm << 16) + (size_t)(r*128 + i*16 + li)*256 + kk*32 + lgp*8);
      for (int j = 0; j < 2; j++)
        a1[i][j] = __builtin_amdgcn_mfma_f32_16x16x32_bf16(Af, Bf[j], a1[i][j], 0, 0, 0);
    }
  }
  for (int i = 0; i < 8; i++)
    for (int j = 0; j < 2; j++){
      int vdl = c*32 + j*16 + li;
      int d1 = r*128 + i*16 + lgp*4;
      int bo2 = (vdl*512 + d1*2) ^ ((vdl & 7) << 4);
      *(unsigned long long*)((char*)TT + bo2) = pk4(a1[i][j][0], a1[i][j][1], a1[i][j][2], a1[i][j][3]);
    }
  __syncthreads();
  // stage 2: mem[kd 256][vd 128] = Wk^T @ T
  f32x4 a2[8][2];
  for (int i = 0; i < 8; i++) for (int j = 0; j < 2; j++) a2[i][j] = (f32x4){0,0,0,0};
  for (int kk = 0; kk < 8; kk++){
    bf16x8 Bf[2];
    for (int j = 0; j < 2; j++){
      int vdl = c*32 + j*16 + li;
      int bo2 = (vdl*512 + (kk*32 + lgp*8)*2) ^ ((vdl & 7) << 4);
      Bf[j] = *(const bf16x8*)((char*)TT + bo2);
    }
    for (int i = 0; i < 8; i++){
      bf16x8 Af = *(const bf16x8*)(WkT + ((size_t)m*2048 + hd0 + r*128 + i*16 + li)*256 + kk*32 + lgp*8);
      for (int j = 0; j < 2; j++)
        a2[i][j] = __builtin_amdgcn_mfma_f32_16x16x32_bf16(Af, Bf[j], a2[i][j], 0, 0, 0);
    }
  }
  __syncthreads();
  // epilogue (rank-1 bias terms) + coalescing bounce
  float rhov = rho[bm];
  unsigned short* Cs = TT;                    // 32 x 264 overlay
  for (int ph = 0; ph < 4; ph++){
    if (c == ph){
      for (int j = 0; j < 2; j++){
        int vdl = c*32 + j*16 + li;
        int vdg = hd0 + vd0 + vdl;
        float bvv = bv[(size_t)m*2048 + vdg];
        float vuv = vu_g[(size_t)bm*2048 + vdg];
        float bb = vuv + rhov * bvv;
        for (int i = 0; i < 8; i++){
          int kd = r*128 + i*16 + lgp*4;
          f32x4 ku4 = *(const f32x4*)(ku_g + (size_t)bm*2048 + hd0 + kd);
          f32x4 bk4 = *(const f32x4*)(bk + (size_t)m*2048 + hd0 + kd);
          float v0 = a2[i][j][0] + ku4[0]*bvv + bk4[0]*bb;
          float v1 = a2[i][j][1] + ku4[1]*bvv + bk4[1]*bb;
          float v2 = a2[i][j][2] + ku4[2]*bvv + bk4[2]*bb;
          float v3 = a2[i][j][3] + ku4[3]*bvv + bk4[3]*bb;
          *(unsigned long long*)(&Cs[(j*16 + li)*264 + kd]) = pk4(v0, v1, v2, v3);
        }
      }
    }
    __syncthreads();
    for (int qq = 0; qq < 2; qq++){
      int idx = t + qq*512;
      int row = idx >> 5, cc = (idx & 31) * 8;
      *(bf16x8*)(mempart + ((size_t)((bh*2 + vq)*8 + m))*32768 + (size_t)(ph*32 + row)*256 + cc) =
        *(const bf16x8*)(&Cs[row*264 + cc]);
    }
    __syncthreads();
  }
}

// =============== reduce mempart over m -> memT[bh][vd][kd] ===============
__global__ __launch_bounds__(256) void k_mred(const unsigned short* __restrict__ mempart,
                                              unsigned short* __restrict__ memT){
  int idx = blockIdx.x * 256 + threadIdx.x;   // 131072
  int bh = idx >> 13; int rem = idx & 8191;
  int vd = rem >> 5, kd0 = (rem & 31) * 8;
  int vq = vd >> 7, vdl = vd & 127;
  size_t src = ((size_t)((bh*2 + vq)*8))*32768 + (size_t)vdl*256 + kd0;
  float s[8] = {0,0,0,0,0,0,0,0};
  for (int m = 0; m < 8; m++){
    bf16x8 v = *(const bf16x8*)(mempart + src + (size_t)m*32768);
    for (int j = 0; j < 8; j++) s[j] += bf2f((unsigned short)v[j]);
  }
  size_t dst = (size_t)bh*65536 + (size_t)vd*256 + kd0;
  *(unsigned long long*)(memT + dst)     = pk4(s[0], s[1], s[2], s[3]);
  *(unsigned long long*)(memT + dst + 4) = pk4(s[4], s[5], s[6], s[7]);
}

// =============== E_h = Wq_h @ mem_h  -> Eb[b][d][h*256+vd]; qbAll = bq_h . mem_h ===============
__global__ __launch_bounds__(512) void k_emat(const unsigned short* __restrict__ memT,
                                              const unsigned short* __restrict__ Wqb,
                                              const float* __restrict__ bq,
                                              unsigned short* __restrict__ Eb,
                                              float* __restrict__ qbAll){
  __shared__ unsigned short Cs[32*264];
  int bid = blockIdx.x;                        // 32 = bh(16) * dseg(2)
  int dseg = bid & 1, bh = bid >> 1;
  int b = bh >> 3, h = bh & 7;
  int hd0 = h * 256, d0 = dseg * 128;
  int t = threadIdx.x, lane = t & 63, w = t >> 6;
  int li = lane & 15, lgp = lane >> 4;
  int r = w >> 2, c = w & 3;
  // out [vd 256][d 128]: A = memT rows vd, B = Wqb rows d (K = kd 256)
  f32x4 acc[8][2];
  for (int i = 0; i < 8; i++) for (int j = 0; j < 2; j++) acc[i][j] = (f32x4){0,0,0,0};
  for (int kk = 0; kk < 8; kk++){
    bf16x8 Bf[2];
    for (int j = 0; j < 2; j++)
      Bf[j] = *(const bf16x8*)(Wqb + (size_t)(d0 + c*32 + j*16 + li)*2048 + hd0 + kk*32 + lgp*8);
    for (int i = 0; i < 8; i++){
      bf16x8 Af = *(const bf16x8*)(memT + (size_t)bh*65536 + (size_t)(r*128 + i*16 + li)*256 + kk*32 + lgp*8);
      for (int j = 0; j < 2; j++)
        acc[i][j] = __builtin_amdgcn_mfma_f32_16x16x32_bf16(Af, Bf[j], acc[i][j], 0, 0, 0);
    }
  }
  // qb: qbAll[b][hd0+vd] = sum_kd bq[hd0+kd]*mem[kd][vd]
  if (dseg == 0 && t < 256){
    const unsigned short* mrow = memT + (size_t)bh*65536 + (size_t)t*256;
    float s = 0.f;
    for (int k8 = 0; k8 < 256; k8 += 8){
      bf16x8 v = *(const bf16x8*)(mrow + k8);
      for (int e = 0; e < 8; e++) s += bf2f((unsigned short)v[e]) * bq[hd0 + k8 + e];
    }
    qbAll[(size_t)b*2048 + hd0 + t] = s;
  }
  // bounce: C row=vd, col=d -> Eb[b][d][hd0+vd]
  for (int ph = 0; ph < 4; ph++){
    if (c == ph){
      for (int i = 0; i < 8; i++)
        for (int j = 0; j < 2; j++){
          int dl = j*16 + li;
          int vd4 = r*128 + i*16 + lgp*4;
          *(unsigned long long*)(&Cs[dl*264 + vd4]) =
            pk4(acc[i][j][0], acc[i][j][1], acc[i][j][2], acc[i][j][3]);
        }
    }
    __syncthreads();
    for (int qq = 0; qq < 2; qq++){
      int idx = t + qq*512;
      int row = idx >> 5, cc = (idx & 31) * 8;
      *(bf16x8*)(Eb + (size_t)b*524288 + (size_t)(d0 + ph*32 + row)*2048 + hd0 + cc) =
        *(const bf16x8*)(&Cs[row*264 + cc]);
    }
    __syncthreads();
  }
}

// =============== F[b][do][d] = Eb[b] x Wo (full K=2048, no atomics); tail: c0 wave-parallel ===============
__global__ __launch_bounds__(512) void k_fmat(const unsigned short* __restrict__ Eb,
                                              const unsigned short* __restrict__ WoT,
                                              const float* __restrict__ qbAll,
                                              const float* __restrict__ bo,
                                              float* __restrict__ Facc,
                                              float* __restrict__ c0acc){
  __shared__ float qL[2048];
  int bid = blockIdx.x;
  int t = threadIdx.x;
  if (bid >= 32){                              // c0 blocks: bid 32,33 -> b (wave-parallel matvec)
    int b = bid - 32;
    for (int i = t; i < 2048; i += 512) qL[i] = qbAll[(size_t)b * 2048 + i];
    __syncthreads();
    int w = t >> 6, lane = t & 63;
    for (int dd = w; dd < 256; dd += 8){
      const unsigned short* wrow = WoT + (size_t)dd * 2048 + lane * 8;
      const float* qp = qL + lane * 8;
      float s = 0.f;
      for (int pass = 0; pass < 4; pass++){
        bf16x8 v = *(const bf16x8*)(wrow + pass * 512);
        const float* q = qp + pass * 512;
        for (int e = 0; e < 8; e++) s += bf2f((unsigned short)v[e]) * q[e];
      }
      for (int off = 32; off; off >>= 1) s += __shfl_down(s, off);
      if (lane == 0) c0acc[(size_t)b * 256 + dd] = s + bo[dd];
    }
    return;
  }
  // F blocks: bid = b*16 + doseg*4 + dseg ; 64x64 tile, K = 2048
  int dseg = bid & 3, doseg = (bid >> 2) & 3, b = bid >> 4;
  int do0 = doseg * 64, d0 = dseg * 64;
  int lane = t & 63, w = t >> 6;
  int li = lane & 15, lgp = lane >> 4;
  int r = w >> 2, c = w & 3;                   // r: do 2x32, c: d 4x16
  f32x4 acc[2];
  acc[0] = (f32x4){0,0,0,0}; acc[1] = (f32x4){0,0,0,0};
  const unsigned short* bp = Eb + (size_t)b*524288 + (size_t)(d0 + c*16 + li)*2048 + lgp*8;
  const unsigned short* ap = WoT + (size_t)(do0 + r*32 + li)*2048 + lgp*8;
  for (int kk = 0; kk < 64; kk++){
    bf16x8 Bf = *(const bf16x8*)(bp + kk*32);
    bf16x8 Af0 = *(const bf16x8*)(ap + kk*32);
    bf16x8 Af1 = *(const bf16x8*)(ap + kk*32 + 16*2048);
    acc[0] = __builtin_amdgcn_mfma_f32_16x16x32_bf16(Af0, Bf, acc[0], 0, 0, 0);
    acc[1] = __builtin_amdgcn_mfma_f32_16x16x32_bf16(Af1, Bf, acc[1], 0, 0, 0);
  }
  int dd = d0 + c*16 + li;
  for (int i = 0; i < 2; i++){
    int dor = do0 + r*32 + i*16 + lgp*4;
    float* p = Facc + (size_t)b*65536 + (size_t)dor*256 + dd;
    p[0]   = acc[i][0];
    p[256] = acc[i][1];
    p[512] = acc[i][2];
    p[768] = acc[i][3];
  }
}

// =============== out[tok][do] = x @ F + c0 (f32 direct) ===============
__global__ __launch_bounds__(512) void k_final2(const float* __restrict__ Facc,
                                                const unsigned short* __restrict__ xb,
                                                const float* __restrict__ c0acc,
                                                float* __restrict__ out){
  int bid = blockIdx.x;                        // 64 = b(2) * tc(32), 64 tokens each
  int tc = bid & 31, b = bid >> 5;
  int t = threadIdx.x, lane = t & 63, w = t >> 6;
  int li = lane & 15, lgp = lane >> 4;
  int r = w >> 1, c = w & 1;                   // r: do 4x64, c: tok 2x32
  int tok0 = b * 2048 + tc * 64;
  f32x4 acc[4][2];
  for (int i = 0; i < 4; i++) for (int j = 0; j < 2; j++) acc[i][j] = (f32x4){0,0,0,0};
  for (int kk = 0; kk < 8; kk++){
    bf16x8 Bf[2];
    for (int j = 0; j < 2; j++)
      Bf[j] = *(const bf16x8*)(xb + (size_t)(tok0 + c*32 + j*16 + li)*256 + kk*32 + lgp*8);
    for (int i = 0; i < 4; i++){
      const float* Fp = Facc + (size_t)b*65536 + (size_t)(r*64 + i*16 + li)*256 + kk*32 + lgp*8;
      f32x4 fa = *(const f32x4*)(Fp);
      f32x4 fb = *(const f32x4*)(Fp + 4);
      union { unsigned long long q[2]; bf16x8 v; } af;
      af.q[0] = pk4(fa[0], fa[1], fa[2], fa[3]);
      af.q[1] = pk4(fb[0], fb[1], fb[2], fb[3]);
      for (int j = 0; j < 2; j++)
        acc[i][j] = __builtin_amdgcn_mfma_f32_16x16x32_bf16(af.v, Bf[j], acc[i][j], 0, 0, 0);
    }
  }
  // C row=do, col=tok: direct f32x4 stores (sector-complete per wave)
  for (int i = 0; i < 4; i++){
    int dol = r*64 + i*16 + lgp*4;
    f32x4 c4 = *(const f32x4*)(c0acc + (size_t)b*256 + dol);
    for (int j = 0; j < 2; j++){
      int tokl = c*32 + j*16 + li;
      f32x4 v = acc[i][j];
      v[0] += c4[0]; v[1] += c4[1]; v[2] += c4[2]; v[3] += c4[3];
      *(f32x4*)(out + (size_t)(tok0 + tokl)*256 + dol) = v;
    }
  }
}

extern "C" void kernel_launch(void* const* d_in, const int* in_sizes, int n_in,
                              void* d_out, int out_size, void* d_ws, size_t ws_size,
                              hipStream_t stream) {
  const float* x     = (const float*)d_in[0];
  const float* Wq    = (const float*)d_in[1];
  const float* bq    = (const float*)d_in[2];
  const float* Wr    = (const float*)d_in[3];
  const float* br    = (const float*)d_in[4];
  const float* Wk    = (const float*)d_in[5];
  const float* bk    = (const float*)d_in[6];
  const float* Wv    = (const float*)d_in[7];
  const float* bv    = (const float*)d_in[8];
  const float* Wo    = (const float*)d_in[9];
  const float* bo    = (const float*)d_in[10];
  const float* bias0 = (const float*)d_in[11];
  float* out = (float*)d_out;

  char* ws = (char*)d_ws;
  size_t off = 0;
  auto alloc = [&](size_t bytes) -> char* {
    char* p = ws + off;
    off = (off + bytes + 255) & ~(size_t)255;
    return p;
  };
  unsigned short* xb   = (unsigned short*)alloc((size_t)4096 * 256 * 2);      // 2 MB
  unsigned short* xT   = (unsigned short*)alloc((size_t)2 * 256 * 2048 * 2);  // 2 MB
  unsigned short* Wqb  = (unsigned short*)alloc((size_t)256 * 2048 * 2);      // 1 MB
  unsigned short* WkT  = (unsigned short*)alloc((size_t)8 * 2048 * 256 * 2);  // 8 MB
  unsigned short* WvT  = (unsigned short*)alloc((size_t)8 * 2048 * 256 * 2);  // 8 MB
  unsigned short* WoT  = (unsigned short*)alloc((size_t)256 * 2048 * 2);      // 1 MB
  float*          routT= (float*)alloc((size_t)16 * 2048 * 4);                // 128 KB
  float*          u    = (float*)alloc((size_t)16 * 256 * 4);                 // 16 KB
  float*          rho  = (float*)alloc((size_t)16 * 4);
  float*          ku_g = (float*)alloc((size_t)16 * 2048 * 4);
  float*          vu_g = (float*)alloc((size_t)16 * 2048 * 4);
  unsigned short* Gp   = (unsigned short*)alloc((size_t)16 * 8 * 65536 * 2);  // 16 MB
  unsigned short* G    = (unsigned short*)alloc((size_t)16 * 65536 * 2);      // 2 MB
  unsigned short* memT = (unsigned short*)alloc((size_t)16 * 65536 * 2);      // 2 MB
  unsigned short* Eb   = (unsigned short*)alloc((size_t)2 * 256 * 2048 * 2);  // 2 MB
  float*          qbAll= (float*)alloc((size_t)2 * 2048 * 4);
  float*          Facc = (float*)alloc((size_t)(2 * 65536 + 2 * 256) * 4);    // F + c0 contiguous
  float*          c0acc= Facc + 2 * 65536;
  unsigned short* mempart = Gp;   // Gp dead after k_gred
  (void)ws_size; (void)in_sizes; (void)n_in; (void)out_size;

  hipMemsetAsync(u, 0, (size_t)16 * 256 * 4 + 256, stream);   // u + rho (contiguous allocs)
  k_prep<<<10112, 256, 0, stream>>>(x, Wq, Wr, br, Wk, Wv, Wo, bias0,
                                    WkT, WvT, WoT, Wqb, xb, xT, routT);
  k_usum<<<256, 256, 0, stream>>>(xb, routT, u, rho);
  k_bias<<<128, 256, 0, stream>>>(WkT, WvT, u, ku_g, vu_g);
  k_gpart<<<128, 512, 0, stream>>>(xT, routT, Gp);
  k_gred<<<512, 256, 0, stream>>>(Gp, G);
  k_memh<<<256, 512, 0, stream>>>(G, WkT, WvT, bk, bv, ku_g, vu_g, rho, mempart);
  k_mred<<<512, 256, 0, stream>>>(mempart, memT);
  k_emat<<<32, 512, 0, stream>>>(memT, Wqb, bq, Eb, qbAll);
  k_fmat<<<34, 512, 0, stream>>>(Eb, WoT, qbAll, bo, Facc, c0acc);
  k_final2<<<64, 512, 0, stream>>>(Facc, xb, c0acc, out);
}